// Round 4
// baseline (1075.657 us; speedup 1.0000x reference)
//
#include <hip/hip_runtime.h>
#include <hip/hip_bf16.h>
#include <math.h>

#define NS   4      // batch
#define CH   128    // channels
#define HW   96     // full-res H=W
#define GS   48     // half-res grid side
#define LL   2304   // GS*GS
#define CKN  2048   // CH*16 (4x4 taps)
#define SCALE 10.0f
#define EPSSUM 0.1152f  // 1152 * 1e-4
#define PCH2 32     // softmax p-chunk (fused into fuse2)
#define NCH2 72     // 2304/32
#define KH   1152   // GEMM2 split-K half

typedef __attribute__((ext_vector_type(8))) short short8;
typedef __attribute__((ext_vector_type(4))) float float4v;

#define GLDS16(gptr, lptr) \
    __builtin_amdgcn_global_load_lds((const __attribute__((address_space(1))) void*)(gptr), \
        (__attribute__((address_space(3))) void*)(lptr), 16, 0, 0)

// ---------------- staging ----------------

__global__ __launch_bounds__(256) void k_stage(const float* __restrict__ b, const float* __restrict__ f,
                                               float* __restrict__ bs_c, float* __restrict__ fs_c) {
    int c  = blockIdx.y;
    int rs = blockIdx.x * 256 + threadIdx.x;     // gridDim.x = 9
    int r = rs / GS, s = rs % GS;
    int src = c * HW * HW + (2 * r) * HW + 2 * s;
    bs_c[c * LL + rs] = b[src];
    fs_c[c * LL + rs] = f[src];
}

// partial ssq over 32 channels per block-row; ssq must be zeroed first (atomic accumulate)
__global__ __launch_bounds__(256) void k_ssq(const float* __restrict__ bs_c, float* __restrict__ ssq) {
    int rs = blockIdx.x * 256 + threadIdx.x;
    int c0 = blockIdx.y * 32;
    float acc = 0.f;
    for (int c = c0; c < c0 + 32; ++c) { float v = bs_c[c * LL + rs]; acc += v * v; }
    atomicAdd(&ssq[rs], acc);
}

__global__ __launch_bounds__(256) void k_norm_mm(const float* __restrict__ ssq, const float* __restrict__ mk,
                                                 float* __restrict__ invn, float* __restrict__ mmv) {
    int p = blockIdx.x * 256 + threadIdx.x;
    int ph = p / GS, pw = p % GS;
    float acc = EPSSUM;
    float msum = 0.f;
    for (int di = -1; di <= 1; ++di)
        for (int dj = -1; dj <= 1; ++dj) {
            int r = ph + di, s = pw + dj;
            if (r >= 0 && r < GS && s >= 0 && s < GS) {
                acc  += ssq[r * GS + s];
                msum += mk[(2 * r) * HW + 2 * s];
            }
        }
    invn[p] = 1.0f / sqrtf(acc);
    mmv[p]  = (msum / 9.0f == 1.0f) ? 1.0f : 0.0f;
}

// W2T[ck][p] = bf16( b[c, 2ph+dy-1, 2pw+dx-1] ), ck = c*16+dy*4+dx
__global__ __launch_bounds__(256) void k_w2T(const float* __restrict__ b, __hip_bfloat16* __restrict__ W2T) {
    int ck = blockIdx.y;
    int p  = blockIdx.x * 256 + threadIdx.x;     // gridDim.x = 9
    int c = ck >> 4, dy = (ck >> 2) & 3, dx = ck & 3;
    int ph = p / GS, pw = p % GS;
    int r = 2 * ph + dy - 1, s = 2 * pw + dx - 1;
    float v = 0.f;
    if (r >= 0 && r < HW && s >= 0 && s < HW) v = b[c * HW * HW + r * HW + s];
    W2T[(size_t)ck * LL + p] = __float2bfloat16(v);
}

// split fp32 [c][rs] -> transposed hi/lo bf16 [rs][c]
__global__ __launch_bounds__(256) void k_split_T(const float* __restrict__ bs_c, const float* __restrict__ fs_c,
                                                 __hip_bfloat16* __restrict__ hiB, __hip_bfloat16* __restrict__ loB,
                                                 __hip_bfloat16* __restrict__ hiF, __hip_bfloat16* __restrict__ loF) {
    __shared__ float tile[32][33];
    const float* X        = blockIdx.z ? fs_c : bs_c;
    __hip_bfloat16* hi    = blockIdx.z ? hiF  : hiB;
    __hip_bfloat16* lo    = blockIdx.z ? loF  : loB;
    int r0 = blockIdx.x * 32, c0 = blockIdx.y * 32;
    int tx = threadIdx.x & 31, ty = threadIdx.x >> 5;
#pragma unroll
    for (int j = 0; j < 4; ++j)
        tile[ty + 8 * j][tx] = X[(size_t)(c0 + ty + 8 * j) * LL + r0 + tx];
    __syncthreads();
#pragma unroll
    for (int j = 0; j < 4; ++j) {
        int rl = ty + 8 * j, cl = tx;
        float v = tile[cl][rl];
        __hip_bfloat16 h = __float2bfloat16(v);
        float resid = v - __bfloat162float(h);
        hi[(size_t)(r0 + rl) * CH + c0 + cl] = h;
        lo[(size_t)(r0 + rl) * CH + c0 + cl] = __float2bfloat16(resid);
    }
}

// ---------------- GEMM1 (split-bf16 MFMA, LDS-swizzled) ----------------
// D[m][n] = sum_k (Ahi+Alo)[m][k]*(Bhi+Blo)[n][k], M=N=2304, K=128, drops lo*lo.
__global__ __launch_bounds__(256) void gemm1_mfma(const __hip_bfloat16* __restrict__ Ahi,
                                                  const __hip_bfloat16* __restrict__ Alo,
                                                  const __hip_bfloat16* __restrict__ Bhi,
                                                  const __hip_bfloat16* __restrict__ Blo,
                                                  float* __restrict__ C) {
    __shared__ __hip_bfloat16 sAh[128 * 32];
    __shared__ __hip_bfloat16 sAl[128 * 32];
    __shared__ __hip_bfloat16 sBh[128 * 32];
    __shared__ __hip_bfloat16 sBl[128 * 32];
    int t = threadIdx.x, lane = t & 63, w = t >> 6;
    int wr = w >> 1, wc = w & 1;
    int m0 = blockIdx.y * 128, n0 = blockIdx.x * 128;

    float4v acc[4][4];
#pragma unroll
    for (int i = 0; i < 4; ++i)
#pragma unroll
        for (int j = 0; j < 4; ++j) acc[i][j] = (float4v){0.f, 0.f, 0.f, 0.f};

    for (int k0 = 0; k0 < 128; k0 += 32) {
#pragma unroll
        for (int it = 0; it < 2; ++it) {
            int chunk = it * 256 + w * 64 + lane;       // LDS slot, lane-contiguous
            int row = chunk >> 2, ps = chunk & 3;
            int pd = ps ^ (row & 3);                    // swizzle: data part stored in slot
            size_t ga = (size_t)(m0 + row) * 128 + k0 + pd * 8;
            size_t gb = (size_t)(n0 + row) * 128 + k0 + pd * 8;
            GLDS16(Ahi + ga, (char*)sAh + (size_t)chunk * 16);
            GLDS16(Alo + ga, (char*)sAl + (size_t)chunk * 16);
            GLDS16(Bhi + gb, (char*)sBh + (size_t)chunk * 16);
            GLDS16(Blo + gb, (char*)sBl + (size_t)chunk * 16);
        }
        __syncthreads();

        int lrow = lane & 15, part = lane >> 4;
        int sw = part ^ (lrow & 3);                     // row&3 == lrow&3 (base multiple of 16)
        short8 ah[4], al[4], bh[4], bl[4];
#pragma unroll
        for (int i = 0; i < 4; ++i) {
            int slot = (wr * 64 + i * 16 + lrow) * 4 + sw;
            ah[i] = *reinterpret_cast<const short8*>(sAh + (size_t)slot * 8);
            al[i] = *reinterpret_cast<const short8*>(sAl + (size_t)slot * 8);
        }
#pragma unroll
        for (int j = 0; j < 4; ++j) {
            int slot = (wc * 64 + j * 16 + lrow) * 4 + sw;
            bh[j] = *reinterpret_cast<const short8*>(sBh + (size_t)slot * 8);
            bl[j] = *reinterpret_cast<const short8*>(sBl + (size_t)slot * 8);
        }
#pragma unroll
        for (int i = 0; i < 4; ++i)
#pragma unroll
            for (int j = 0; j < 4; ++j) {
                acc[i][j] = __builtin_amdgcn_mfma_f32_16x16x32_bf16(ah[i], bh[j], acc[i][j], 0, 0, 0);
                acc[i][j] = __builtin_amdgcn_mfma_f32_16x16x32_bf16(ah[i], bl[j], acc[i][j], 0, 0, 0);
                acc[i][j] = __builtin_amdgcn_mfma_f32_16x16x32_bf16(al[i], bh[j], acc[i][j], 0, 0, 0);
            }
        __syncthreads();
    }

    int col = lane & 15, rbase = (lane >> 4) * 4;
#pragma unroll
    for (int i = 0; i < 4; ++i)
#pragma unroll
        for (int j = 0; j < 4; ++j)
#pragma unroll
            for (int r = 0; r < 4; ++r) {
                int m = m0 + wr * 64 + i * 16 + rbase + r;
                int n = n0 + wc * 64 + j * 16 + col;
                C[(size_t)m * LL + n] = acc[i][j][r];
            }
}

// ---------------- GEMM2 (bf16 MFMA, split-K(2), LDS-swizzled) ----------------
// Zs[m][n] = sum_{k in half z} A[m][k]*B[n][k]; A=[M][K] attnT, B=[N][K] W2T, K=2304.
__global__ __launch_bounds__(256) void gemm2_mfma(const __hip_bfloat16* __restrict__ A,
                                                  const __hip_bfloat16* __restrict__ B,
                                                  float* __restrict__ Z0, float* __restrict__ Z1,
                                                  int M, int N, int K) {
    __shared__ __hip_bfloat16 As[128 * 32];
    __shared__ __hip_bfloat16 Bs[128 * 32];
    int t = threadIdx.x;
    int lane = t & 63, w = t >> 6;
    int wr = w >> 1, wc = w & 1;
    int m0 = blockIdx.y * 128, n0 = blockIdx.x * 128;
    int z = blockIdx.z;
    float* C = z ? Z1 : Z0;

    float4v acc[4][4];
#pragma unroll
    for (int i = 0; i < 4; ++i)
#pragma unroll
        for (int j = 0; j < 4; ++j) acc[i][j] = (float4v){0.f, 0.f, 0.f, 0.f};

    for (int k0 = z * KH; k0 < z * KH + KH; k0 += 32) {
#pragma unroll
        for (int it = 0; it < 2; ++it) {
            int chunk = it * 256 + w * 64 + lane;
            int row = chunk >> 2, ps = chunk & 3;
            int pd = ps ^ (row & 3);
            const __hip_bfloat16* ga = A + (size_t)(m0 + row) * K + k0 + pd * 8;
            const __hip_bfloat16* gb = B + (size_t)(n0 + row) * K + k0 + pd * 8;
            GLDS16(ga, (char*)As + (size_t)chunk * 16);
            GLDS16(gb, (char*)Bs + (size_t)chunk * 16);
        }
        __syncthreads();

        int lrow = lane & 15, part = lane >> 4;
        int sw = part ^ (lrow & 3);
        short8 afrag[4], bfrag[4];
#pragma unroll
        for (int i = 0; i < 4; ++i) {
            int slot = (wr * 64 + i * 16 + lrow) * 4 + sw;
            afrag[i] = *reinterpret_cast<const short8*>(As + (size_t)slot * 8);
        }
#pragma unroll
        for (int j = 0; j < 4; ++j) {
            int slot = (wc * 64 + j * 16 + lrow) * 4 + sw;
            bfrag[j] = *reinterpret_cast<const short8*>(Bs + (size_t)slot * 8);
        }
#pragma unroll
        for (int i = 0; i < 4; ++i)
#pragma unroll
            for (int j = 0; j < 4; ++j)
                acc[i][j] = __builtin_amdgcn_mfma_f32_16x16x32_bf16(afrag[i], bfrag[j], acc[i][j], 0, 0, 0);
        __syncthreads();
    }

    int col = lane & 15, rbase = (lane >> 4) * 4;
#pragma unroll
    for (int i = 0; i < 4; ++i)
#pragma unroll
        for (int j = 0; j < 4; ++j)
#pragma unroll
            for (int r = 0; r < 4; ++r) {
                int m = m0 + wr * 64 + i * 16 + rbase + r;
                int n = n0 + wc * 64 + j * 16 + col;
                C[(size_t)m * N + n] = acc[i][j][r];
            }
}

// ---------------- fused corr + fuse1: S1 directly from D ----------------
// S1[a][b] = sum_{d=-1..1, a+d,b+d in [0,LL)} invn[a+d] * sum_{di,dj 2D-valid} D[a+d+48di+dj][b+d+48di+dj]
__global__ __launch_bounds__(256) void k_corr_fuse1(const float* __restrict__ D, const float* __restrict__ invn,
                                                    float* __restrict__ S1) {
    int a = blockIdx.y;
    int b = blockIdx.x * 256 + threadIdx.x;
    float s = 0.f;
#pragma unroll
    for (int d = -1; d <= 1; ++d) {
        int p = a + d, q = b + d;
        if (p < 0 || p >= LL) continue;                 // scalar (a uniform)
        if (q < 0 || q >= LL) continue;
        int ph = p / GS, pw = p % GS;                   // scalar
        int qh = q / GS, qw = q % GS;
        float inv = invn[p];                            // scalar load
        float c = 0.f;
#pragma unroll
        for (int di = -1; di <= 1; ++di) {
            if ((unsigned)(ph + di) >= GS) continue;    // scalar test
#pragma unroll
            for (int dj = -1; dj <= 1; ++dj) {
                if ((unsigned)(pw + dj) >= GS) continue; // scalar test
                bool ok = ((unsigned)(qh + di) < GS) & ((unsigned)(qw + dj) < GS);
                int sh = di * GS + dj;
                float v = ok ? D[(size_t)(p + sh) * LL + q + sh] : 0.f;
                c += v;
            }
        }
        s = fmaf(inv, c, s);
    }
    S1[(size_t)a * LL + b] = s;
}

__device__ __forceinline__ int gmap(int x) { int hi = x / GS; int lo = x - hi * GS; return lo * GS + hi; }

// fuse2 + softmax partials
__global__ __launch_bounds__(256) void k_fuse2_sm(const float* __restrict__ S1, const float* __restrict__ mmv,
                                                  float* __restrict__ S2,
                                                  float* __restrict__ pmax, float* __restrict__ psum) {
    int q = blockIdx.x * 256 + threadIdx.x;
    int qh = q / GS, qw = q % GS;
    int b0 = qw * GS + qh;
    int p0 = blockIdx.y * PCH2;
    float mx = -1e30f, sm = 0.f;
    for (int i = 0; i < PCH2; ++i) {
        int p = p0 + i;
        int ph = p / GS, pw = p % GS;
        int a0 = pw * GS + ph;
        float s = 0.f;
#pragma unroll
        for (int e = -1; e <= 1; ++e) {
            int ae = a0 + e, be = b0 + e;
            if (ae >= 0 && ae < LL && be >= 0 && be < LL)
                s += S1[(size_t)gmap(ae) * LL + gmap(be)];
        }
        S2[(size_t)p * LL + q] = s;
        float lg = (mmv[p] != 0.f) ? SCALE * s : 0.f;
        float nm = fmaxf(mx, lg);
        sm = sm * __expf(mx - nm) + __expf(lg - nm);
        mx = nm;
    }
    pmax[blockIdx.y * LL + q] = mx;
    psum[blockIdx.y * LL + q] = sm;
}

// final softmax max/denominator: 4-way parallel tree over 72 chunks, 64 q per block
__global__ __launch_bounds__(256) void k_sm2(const float* __restrict__ pmax, const float* __restrict__ psum,
                                             float* __restrict__ Mq, float* __restrict__ Dq) {
    __shared__ float red[4][64];
    int t = threadIdx.x;
    int ql = t & 63, g = t >> 6;
    int q = blockIdx.x * 64 + ql;
    float mx = -1e30f;
    for (int ch = g * 18; ch < g * 18 + 18; ++ch) mx = fmaxf(mx, pmax[(size_t)ch * LL + q]);
    red[g][ql] = mx;
    __syncthreads();
    float mall = fmaxf(fmaxf(red[0][ql], red[1][ql]), fmaxf(red[2][ql], red[3][ql]));
    float sm = 0.f;
    for (int ch = g * 18; ch < g * 18 + 18; ++ch)
        sm += psum[(size_t)ch * LL + q] * __expf(pmax[(size_t)ch * LL + q] - mall);
    __syncthreads();
    red[g][ql] = sm;
    __syncthreads();
    if (g == 0) {
        Mq[q] = mall;
        Dq[q] = (red[0][ql] + red[1][ql]) + (red[2][ql] + red[3][ql]);
    }
}

// attnT[q][p] = bf16( mmv[p] * exp(10*S2[p][q] - Mq[q]) / Dq[q] ) via 32x32 LDS transpose
__global__ __launch_bounds__(256) void k_sm3T(const float* __restrict__ S2, const float* __restrict__ mmv,
                                              const float* __restrict__ Mq, const float* __restrict__ Dq,
                                              __hip_bfloat16* __restrict__ attnT) {
    __shared__ float tile[32][33];
    int tx = threadIdx.x & 31, ty = threadIdx.x >> 5;
    int p0 = blockIdx.y * 32, q0 = blockIdx.x * 32;
    int q = q0 + tx;
    float mq = Mq[q], dq = Dq[q];
#pragma unroll
    for (int j = 0; j < 4; ++j) {
        int p = p0 + ty + 8 * j;
        float v = S2[(size_t)p * LL + q];
        float attn = (mmv[p] != 0.f) ? __expf(SCALE * v - mq) / dq : 0.f;
        tile[ty + 8 * j][tx] = attn;
    }
    __syncthreads();
#pragma unroll
    for (int j = 0; j < 4; ++j) {
        int qq = q0 + ty + 8 * j;
        attnT[(size_t)qq * LL + p0 + tx] = __float2bfloat16(tile[tx][ty + 8 * j]);
    }
}

// ---------------- output assembly (sums split-K halves) ----------------
__global__ __launch_bounds__(256) void k_out(const float* __restrict__ Z0, const float* __restrict__ Z1,
                                             float* __restrict__ out) {
    int c  = blockIdx.y;
    int yx = blockIdx.x * 256 + threadIdx.x;     // gridDim.x = 36
    int y = yx / HW, x = yx % HW;
    int u = y >> 1, a = y & 1, v = x >> 1, w = x & 1;
    int qh1 = u + a - 1, qh2 = u + a, qw1 = v + w - 1, qw2 = v + w;
    int cb = c * 16;
    float s = 0.f;
    if (qh1 >= 0) {
        if (qw1 >= 0) { size_t i0 = (size_t)(qh1 * GS + qw1) * CKN + cb + (3 - a) * 4 + (3 - w); s += Z0[i0] + Z1[i0]; }
        if (qw2 < GS) { size_t i1 = (size_t)(qh1 * GS + qw2) * CKN + cb + (3 - a) * 4 + (1 - w); s += Z0[i1] + Z1[i1]; }
    }
    if (qh2 < GS) {
        if (qw1 >= 0) { size_t i2 = (size_t)(qh2 * GS + qw1) * CKN + cb + (1 - a) * 4 + (3 - w); s += Z0[i2] + Z1[i2]; }
        if (qw2 < GS) { size_t i3 = (size_t)(qh2 * GS + qw2) * CKN + cb + (1 - a) * 4 + (1 - w); s += Z0[i3] + Z1[i3]; }
    }
    out[(size_t)c * HW * HW + yx] = 0.25f * s;
}

// ---------------- launch ----------------

extern "C" void kernel_launch(void* const* d_in, const int* in_sizes, int n_in,
                              void* d_out, int out_size, void* d_ws, size_t ws_size,
                              hipStream_t stream) {
    const float* b_all = (const float*)d_in[0];
    const float* f_all = (const float*)d_in[1];
    const float* m_all = (const float*)d_in[2];
    float* out = (float*)d_out;
    float* ws  = (float*)d_ws;

    size_t off = 0;
    float* bs_c = ws + off; off += (size_t)CH * LL;
    float* fs_c = ws + off; off += (size_t)CH * LL;
    float* ssq  = ws + off; off += LL;
    float* invn = ws + off; off += LL;
    float* mmv  = ws + off; off += LL;
    float* Mq   = ws + off; off += LL;
    float* Dq   = ws + off; off += LL;
    float* pmax = ws + off; off += (size_t)NCH2 * LL;
    float* psum = ws + off; off += (size_t)NCH2 * LL;
    float* bufA = ws + off; off += (size_t)LL * LL;   // D -> S2 -> Z1
    float* bufB = ws + off; off += (size_t)LL * LL;   // (splits) -> S1 -> Z0
    __hip_bfloat16* W2T   = (__hip_bfloat16*)(ws + off); off += (size_t)CKN * LL / 2;
    __hip_bfloat16* attnT = (__hip_bfloat16*)(ws + off); off += (size_t)LL * LL / 2;

    // split-bf16 operands for GEMM1, aliased into bufB (dead until corr_fuse1 writes S1)
    __hip_bfloat16* bsT_hi = (__hip_bfloat16*)bufB;
    __hip_bfloat16* bsT_lo = bsT_hi + (size_t)LL * CH;
    __hip_bfloat16* fsT_hi = bsT_lo + (size_t)LL * CH;
    __hip_bfloat16* fsT_lo = fsT_hi + (size_t)LL * CH;

    for (int i = 0; i < NS; ++i) {
        const float* b  = b_all + (size_t)i * CH * HW * HW;
        const float* f  = f_all + (size_t)i * CH * HW * HW;
        const float* mk = m_all + (size_t)i * HW * HW;
        float* outp = out + (size_t)i * CH * HW * HW;

        hipMemsetAsync(ssq, 0, LL * sizeof(float), stream);
        k_stage    <<<dim3(9, CH), 256, 0, stream>>>(b, f, bs_c, fs_c);
        k_ssq      <<<dim3(9, 4), 256, 0, stream>>>(bs_c, ssq);
        k_norm_mm  <<<9, 256, 0, stream>>>(ssq, mk, invn, mmv);
        k_w2T      <<<dim3(9, CKN), 256, 0, stream>>>(b, W2T);
        k_split_T  <<<dim3(72, 4, 2), 256, 0, stream>>>(bs_c, fs_c, bsT_hi, bsT_lo, fsT_hi, fsT_lo);

        // GEMM1: D[p][q] = sum_c bs[p][c]*fs[q][c]  (split-bf16 MFMA) -> bufA
        gemm1_mfma <<<dim3(18, 18), 256, 0, stream>>>(bsT_hi, bsT_lo, fsT_hi, fsT_lo, bufA);
        // fused corr+fuse1: bufA -> S1 (bufB)
        k_corr_fuse1<<<dim3(9, LL), 256, 0, stream>>>(bufA, invn, bufB);
        // fuse2 + softmax partials: S1 (bufB) -> S2 (bufA)
        k_fuse2_sm <<<dim3(9, NCH2), 256, 0, stream>>>(bufB, mmv, bufA, pmax, psum);

        k_sm2      <<<36, 256, 0, stream>>>(pmax, psum, Mq, Dq);
        k_sm3T     <<<dim3(72, 72), 256, 0, stream>>>(bufA, mmv, Mq, Dq, attnT);

        // GEMM2 (bf16 MFMA, split-K 2): Z0 -> bufB, Z1 -> bufA
        gemm2_mfma <<<dim3(CKN / 128, LL / 128, 2), 256, 0, stream>>>(attnT, W2T, bufB, bufA, LL, CKN, LL);
        k_out      <<<dim3(36, CH), 256, 0, stream>>>(bufB, bufA, outp);
    }
}

// Round 5
// 962.016 us; speedup vs baseline: 1.1181x; 1.1181x over previous
//
#include <hip/hip_runtime.h>
#include <hip/hip_bf16.h>
#include <math.h>

#define NS   4      // batch
#define CH   128    // channels
#define HW   96     // full-res H=W
#define GS   48     // half-res grid side
#define LL   2304   // GS*GS
#define CKN  2048   // CH*16 (4x4 taps)
#define SCALE 10.0f
#define EPSSUM 0.1152f  // 1152 * 1e-4
#define PCH2 32     // softmax p-chunk (fused into fuse2)
#define NCH2 72     // 2304/32
#define KH   1152   // GEMM2 split-K half

typedef __attribute__((ext_vector_type(8))) short short8;
typedef __attribute__((ext_vector_type(4))) float float4v;

#define GLDS16(gptr, lptr) \
    __builtin_amdgcn_global_load_lds((const __attribute__((address_space(1))) void*)(gptr), \
        (__attribute__((address_space(3))) void*)(lptr), 16, 0, 0)

// ---------------- staging ----------------

__global__ __launch_bounds__(256) void k_stage(const float* __restrict__ b, const float* __restrict__ f,
                                               float* __restrict__ bs_c, float* __restrict__ fs_c) {
    int c  = blockIdx.y;
    int rs = blockIdx.x * 256 + threadIdx.x;     // gridDim.x = 9
    int r = rs / GS, s = rs % GS;
    int src = c * HW * HW + (2 * r) * HW + 2 * s;
    bs_c[c * LL + rs] = b[src];
    fs_c[c * LL + rs] = f[src];
}

// partial ssq over 32 channels per block-row; ssq zeroed first (atomic accumulate)
__global__ __launch_bounds__(256) void k_ssq(const float* __restrict__ bs_c, float* __restrict__ ssq) {
    int rs = blockIdx.x * 256 + threadIdx.x;
    int c0 = blockIdx.y * 32;
    float acc = 0.f;
    for (int c = c0; c < c0 + 32; ++c) { float v = bs_c[c * LL + rs]; acc += v * v; }
    atomicAdd(&ssq[rs], acc);
}

__global__ __launch_bounds__(256) void k_norm_mm(const float* __restrict__ ssq, const float* __restrict__ mk,
                                                 float* __restrict__ invn, float* __restrict__ mmv) {
    int p = blockIdx.x * 256 + threadIdx.x;
    int ph = p / GS, pw = p % GS;
    float acc = EPSSUM;
    float msum = 0.f;
    for (int di = -1; di <= 1; ++di)
        for (int dj = -1; dj <= 1; ++dj) {
            int r = ph + di, s = pw + dj;
            if (r >= 0 && r < GS && s >= 0 && s < GS) {
                acc  += ssq[r * GS + s];
                msum += mk[(2 * r) * HW + 2 * s];
            }
        }
    invn[p] = 1.0f / sqrtf(acc);
    mmv[p]  = (msum / 9.0f == 1.0f) ? 1.0f : 0.0f;
}

// W2T[ck][p] = bf16( b[c, 2ph+dy-1, 2pw+dx-1] ), ck = c*16+dy*4+dx
__global__ __launch_bounds__(256) void k_w2T(const float* __restrict__ b, __hip_bfloat16* __restrict__ W2T) {
    int ck = blockIdx.y;
    int p  = blockIdx.x * 256 + threadIdx.x;     // gridDim.x = 9
    int c = ck >> 4, dy = (ck >> 2) & 3, dx = ck & 3;
    int ph = p / GS, pw = p % GS;
    int r = 2 * ph + dy - 1, s = 2 * pw + dx - 1;
    float v = 0.f;
    if (r >= 0 && r < HW && s >= 0 && s < HW) v = b[c * HW * HW + r * HW + s];
    W2T[(size_t)ck * LL + p] = __float2bfloat16(v);
}

// split fp32 [c][rs] -> transposed hi/lo bf16 [rs][c]
__global__ __launch_bounds__(256) void k_split_T(const float* __restrict__ bs_c, const float* __restrict__ fs_c,
                                                 __hip_bfloat16* __restrict__ hiB, __hip_bfloat16* __restrict__ loB,
                                                 __hip_bfloat16* __restrict__ hiF, __hip_bfloat16* __restrict__ loF) {
    __shared__ float tile[32][33];
    const float* X        = blockIdx.z ? fs_c : bs_c;
    __hip_bfloat16* hi    = blockIdx.z ? hiF  : hiB;
    __hip_bfloat16* lo    = blockIdx.z ? loF  : loB;
    int r0 = blockIdx.x * 32, c0 = blockIdx.y * 32;
    int tx = threadIdx.x & 31, ty = threadIdx.x >> 5;
#pragma unroll
    for (int j = 0; j < 4; ++j)
        tile[ty + 8 * j][tx] = X[(size_t)(c0 + ty + 8 * j) * LL + r0 + tx];
    __syncthreads();
#pragma unroll
    for (int j = 0; j < 4; ++j) {
        int rl = ty + 8 * j, cl = tx;
        float v = tile[cl][rl];
        __hip_bfloat16 h = __float2bfloat16(v);
        float resid = v - __bfloat162float(h);
        hi[(size_t)(r0 + rl) * CH + c0 + cl] = h;
        lo[(size_t)(r0 + rl) * CH + c0 + cl] = __float2bfloat16(resid);
    }
}

// ---------------- GEMM1 (split-bf16 MFMA, LDS-swizzled) ----------------
__global__ __launch_bounds__(256) void gemm1_mfma(const __hip_bfloat16* __restrict__ Ahi,
                                                  const __hip_bfloat16* __restrict__ Alo,
                                                  const __hip_bfloat16* __restrict__ Bhi,
                                                  const __hip_bfloat16* __restrict__ Blo,
                                                  float* __restrict__ C) {
    __shared__ __hip_bfloat16 sAh[128 * 32];
    __shared__ __hip_bfloat16 sAl[128 * 32];
    __shared__ __hip_bfloat16 sBh[128 * 32];
    __shared__ __hip_bfloat16 sBl[128 * 32];
    int t = threadIdx.x, lane = t & 63, w = t >> 6;
    int wr = w >> 1, wc = w & 1;
    int m0 = blockIdx.y * 128, n0 = blockIdx.x * 128;

    float4v acc[4][4];
#pragma unroll
    for (int i = 0; i < 4; ++i)
#pragma unroll
        for (int j = 0; j < 4; ++j) acc[i][j] = (float4v){0.f, 0.f, 0.f, 0.f};

    for (int k0 = 0; k0 < 128; k0 += 32) {
#pragma unroll
        for (int it = 0; it < 2; ++it) {
            int chunk = it * 256 + w * 64 + lane;
            int row = chunk >> 2, ps = chunk & 3;
            int pd = ps ^ (row & 3);
            size_t ga = (size_t)(m0 + row) * 128 + k0 + pd * 8;
            size_t gb = (size_t)(n0 + row) * 128 + k0 + pd * 8;
            GLDS16(Ahi + ga, (char*)sAh + (size_t)chunk * 16);
            GLDS16(Alo + ga, (char*)sAl + (size_t)chunk * 16);
            GLDS16(Bhi + gb, (char*)sBh + (size_t)chunk * 16);
            GLDS16(Blo + gb, (char*)sBl + (size_t)chunk * 16);
        }
        __syncthreads();

        int lrow = lane & 15, part = lane >> 4;
        int sw = part ^ (lrow & 3);
        short8 ah[4], al[4], bh[4], bl[4];
#pragma unroll
        for (int i = 0; i < 4; ++i) {
            int slot = (wr * 64 + i * 16 + lrow) * 4 + sw;
            ah[i] = *reinterpret_cast<const short8*>(sAh + (size_t)slot * 8);
            al[i] = *reinterpret_cast<const short8*>(sAl + (size_t)slot * 8);
        }
#pragma unroll
        for (int j = 0; j < 4; ++j) {
            int slot = (wc * 64 + j * 16 + lrow) * 4 + sw;
            bh[j] = *reinterpret_cast<const short8*>(sBh + (size_t)slot * 8);
            bl[j] = *reinterpret_cast<const short8*>(sBl + (size_t)slot * 8);
        }
#pragma unroll
        for (int i = 0; i < 4; ++i)
#pragma unroll
            for (int j = 0; j < 4; ++j) {
                acc[i][j] = __builtin_amdgcn_mfma_f32_16x16x32_bf16(ah[i], bh[j], acc[i][j], 0, 0, 0);
                acc[i][j] = __builtin_amdgcn_mfma_f32_16x16x32_bf16(ah[i], bl[j], acc[i][j], 0, 0, 0);
                acc[i][j] = __builtin_amdgcn_mfma_f32_16x16x32_bf16(al[i], bh[j], acc[i][j], 0, 0, 0);
            }
        __syncthreads();
    }

    int col = lane & 15, rbase = (lane >> 4) * 4;
#pragma unroll
    for (int i = 0; i < 4; ++i)
#pragma unroll
        for (int j = 0; j < 4; ++j)
#pragma unroll
            for (int r = 0; r < 4; ++r) {
                int m = m0 + wr * 64 + i * 16 + rbase + r;
                int n = n0 + wc * 64 + j * 16 + col;
                C[(size_t)m * LL + n] = acc[i][j][r];
            }
}

// ---------------- GEMM2 (bf16 MFMA, split-K(2), LDS-swizzled) ----------------
__global__ __launch_bounds__(256) void gemm2_mfma(const __hip_bfloat16* __restrict__ A,
                                                  const __hip_bfloat16* __restrict__ B,
                                                  float* __restrict__ Z0, float* __restrict__ Z1,
                                                  int M, int N, int K) {
    __shared__ __hip_bfloat16 As[128 * 32];
    __shared__ __hip_bfloat16 Bs[128 * 32];
    int t = threadIdx.x;
    int lane = t & 63, w = t >> 6;
    int wr = w >> 1, wc = w & 1;
    int m0 = blockIdx.y * 128, n0 = blockIdx.x * 128;
    int z = blockIdx.z;
    float* C = z ? Z1 : Z0;

    float4v acc[4][4];
#pragma unroll
    for (int i = 0; i < 4; ++i)
#pragma unroll
        for (int j = 0; j < 4; ++j) acc[i][j] = (float4v){0.f, 0.f, 0.f, 0.f};

    for (int k0 = z * KH; k0 < z * KH + KH; k0 += 32) {
#pragma unroll
        for (int it = 0; it < 2; ++it) {
            int chunk = it * 256 + w * 64 + lane;
            int row = chunk >> 2, ps = chunk & 3;
            int pd = ps ^ (row & 3);
            const __hip_bfloat16* ga = A + (size_t)(m0 + row) * K + k0 + pd * 8;
            const __hip_bfloat16* gb = B + (size_t)(n0 + row) * K + k0 + pd * 8;
            GLDS16(ga, (char*)As + (size_t)chunk * 16);
            GLDS16(gb, (char*)Bs + (size_t)chunk * 16);
        }
        __syncthreads();

        int lrow = lane & 15, part = lane >> 4;
        int sw = part ^ (lrow & 3);
        short8 afrag[4], bfrag[4];
#pragma unroll
        for (int i = 0; i < 4; ++i) {
            int slot = (wr * 64 + i * 16 + lrow) * 4 + sw;
            afrag[i] = *reinterpret_cast<const short8*>(As + (size_t)slot * 8);
        }
#pragma unroll
        for (int j = 0; j < 4; ++j) {
            int slot = (wc * 64 + j * 16 + lrow) * 4 + sw;
            bfrag[j] = *reinterpret_cast<const short8*>(Bs + (size_t)slot * 8);
        }
#pragma unroll
        for (int i = 0; i < 4; ++i)
#pragma unroll
            for (int j = 0; j < 4; ++j)
                acc[i][j] = __builtin_amdgcn_mfma_f32_16x16x32_bf16(afrag[i], bfrag[j], acc[i][j], 0, 0, 0);
        __syncthreads();
    }

    int col = lane & 15, rbase = (lane >> 4) * 4;
#pragma unroll
    for (int i = 0; i < 4; ++i)
#pragma unroll
        for (int j = 0; j < 4; ++j)
#pragma unroll
            for (int r = 0; r < 4; ++r) {
                int m = m0 + wr * 64 + i * 16 + rbase + r;
                int n = n0 + wc * 64 + j * 16 + col;
                C[(size_t)m * N + n] = acc[i][j][r];
            }
}

// ---------------- correlation assembly + fuses (separate — fused version regressed 3.4x) ----------------

__global__ __launch_bounds__(256) void k_corr(const float* __restrict__ D, const float* __restrict__ invn,
                                              float* __restrict__ yi) {
    int p = blockIdx.y;
    int q = blockIdx.x * 256 + threadIdx.x;
    int ph = p / GS, pw = p % GS, qh = q / GS, qw = q % GS;
    float s = 0.f;
#pragma unroll
    for (int di = -1; di <= 1; ++di) {
        int rp = ph + di, tq = qh + di;
        if (rp < 0 || rp >= GS || tq < 0 || tq >= GS) continue;
#pragma unroll
        for (int dj = -1; dj <= 1; ++dj) {
            int sp = pw + dj, uq = qw + dj;
            if (sp < 0 || sp >= GS || uq < 0 || uq >= GS) continue;
            s += D[(size_t)(rp * GS + sp) * LL + (tq * GS + uq)];
        }
    }
    yi[(size_t)p * LL + q] = invn[p] * s;
}

__global__ __launch_bounds__(256) void k_fuse1(const float* __restrict__ yi, float* __restrict__ S1) {
    int a = blockIdx.y;
    int bcol = blockIdx.x * 256 + threadIdx.x;
    float s = 0.f;
#pragma unroll
    for (int d = -1; d <= 1; ++d) {
        int aa = a + d, bb = bcol + d;
        if (aa >= 0 && aa < LL && bb >= 0 && bb < LL) s += yi[(size_t)aa * LL + bb];
    }
    S1[(size_t)a * LL + bcol] = s;
}

__device__ __forceinline__ int gmap(int x) { int hi = x / GS; int lo = x - hi * GS; return lo * GS + hi; }

// fuse2 + softmax partials
__global__ __launch_bounds__(256) void k_fuse2_sm(const float* __restrict__ S1, const float* __restrict__ mmv,
                                                  float* __restrict__ S2,
                                                  float* __restrict__ pmax, float* __restrict__ psum) {
    int q = blockIdx.x * 256 + threadIdx.x;
    int qh = q / GS, qw = q % GS;
    int b0 = qw * GS + qh;
    int p0 = blockIdx.y * PCH2;
    float mx = -1e30f, sm = 0.f;
    for (int i = 0; i < PCH2; ++i) {
        int p = p0 + i;
        int ph = p / GS, pw = p % GS;
        int a0 = pw * GS + ph;
        float s = 0.f;
#pragma unroll
        for (int e = -1; e <= 1; ++e) {
            int ae = a0 + e, be = b0 + e;
            if (ae >= 0 && ae < LL && be >= 0 && be < LL)
                s += S1[(size_t)gmap(ae) * LL + gmap(be)];
        }
        S2[(size_t)p * LL + q] = s;
        float lg = (mmv[p] != 0.f) ? SCALE * s : 0.f;
        float nm = fmaxf(mx, lg);
        sm = sm * __expf(mx - nm) + __expf(lg - nm);
        mx = nm;
    }
    pmax[blockIdx.y * LL + q] = mx;
    psum[blockIdx.y * LL + q] = sm;
}

// final softmax max/denominator: 4-way tree over 72 chunks, 64 q per block
__global__ __launch_bounds__(256) void k_sm2(const float* __restrict__ pmax, const float* __restrict__ psum,
                                             float* __restrict__ Mq, float* __restrict__ Dq) {
    __shared__ float red[4][64];
    int t = threadIdx.x;
    int ql = t & 63, g = t >> 6;
    int q = blockIdx.x * 64 + ql;
    float mx = -1e30f;
    for (int ch = g * 18; ch < g * 18 + 18; ++ch) mx = fmaxf(mx, pmax[(size_t)ch * LL + q]);
    red[g][ql] = mx;
    __syncthreads();
    float mall = fmaxf(fmaxf(red[0][ql], red[1][ql]), fmaxf(red[2][ql], red[3][ql]));
    float sm = 0.f;
    for (int ch = g * 18; ch < g * 18 + 18; ++ch)
        sm += psum[(size_t)ch * LL + q] * __expf(pmax[(size_t)ch * LL + q] - mall);
    __syncthreads();
    red[g][ql] = sm;
    __syncthreads();
    if (g == 0) {
        Mq[q] = mall;
        Dq[q] = (red[0][ql] + red[1][ql]) + (red[2][ql] + red[3][ql]);
    }
}

// attnT[q][p] = bf16( mmv[p] * exp(10*S2[p][q] - Mq[q]) / Dq[q] ) via 32x32 LDS transpose
__global__ __launch_bounds__(256) void k_sm3T(const float* __restrict__ S2, const float* __restrict__ mmv,
                                              const float* __restrict__ Mq, const float* __restrict__ Dq,
                                              __hip_bfloat16* __restrict__ attnT) {
    __shared__ float tile[32][33];
    int tx = threadIdx.x & 31, ty = threadIdx.x >> 5;
    int p0 = blockIdx.y * 32, q0 = blockIdx.x * 32;
    int q = q0 + tx;
    float mq = Mq[q], dq = Dq[q];
#pragma unroll
    for (int j = 0; j < 4; ++j) {
        int p = p0 + ty + 8 * j;
        float v = S2[(size_t)p * LL + q];
        float attn = (mmv[p] != 0.f) ? __expf(SCALE * v - mq) / dq : 0.f;
        tile[ty + 8 * j][tx] = attn;
    }
    __syncthreads();
#pragma unroll
    for (int j = 0; j < 4; ++j) {
        int qq = q0 + ty + 8 * j;
        attnT[(size_t)qq * LL + p0 + tx] = __float2bfloat16(tile[tx][ty + 8 * j]);
    }
}

// ---------------- output assembly (sums split-K halves) ----------------
__global__ __launch_bounds__(256) void k_out(const float* __restrict__ Z0, const float* __restrict__ Z1,
                                             float* __restrict__ out) {
    int c  = blockIdx.y;
    int yx = blockIdx.x * 256 + threadIdx.x;     // gridDim.x = 36
    int y = yx / HW, x = yx % HW;
    int u = y >> 1, a = y & 1, v = x >> 1, w = x & 1;
    int qh1 = u + a - 1, qh2 = u + a, qw1 = v + w - 1, qw2 = v + w;
    int cb = c * 16;
    float s = 0.f;
    if (qh1 >= 0) {
        if (qw1 >= 0) { size_t i0 = (size_t)(qh1 * GS + qw1) * CKN + cb + (3 - a) * 4 + (3 - w); s += Z0[i0] + Z1[i0]; }
        if (qw2 < GS) { size_t i1 = (size_t)(qh1 * GS + qw2) * CKN + cb + (3 - a) * 4 + (1 - w); s += Z0[i1] + Z1[i1]; }
    }
    if (qh2 < GS) {
        if (qw1 >= 0) { size_t i2 = (size_t)(qh2 * GS + qw1) * CKN + cb + (1 - a) * 4 + (3 - w); s += Z0[i2] + Z1[i2]; }
        if (qw2 < GS) { size_t i3 = (size_t)(qh2 * GS + qw2) * CKN + cb + (1 - a) * 4 + (1 - w); s += Z0[i3] + Z1[i3]; }
    }
    out[(size_t)c * HW * HW + yx] = 0.25f * s;
}

// ---------------- launch ----------------

extern "C" void kernel_launch(void* const* d_in, const int* in_sizes, int n_in,
                              void* d_out, int out_size, void* d_ws, size_t ws_size,
                              hipStream_t stream) {
    const float* b_all = (const float*)d_in[0];
    const float* f_all = (const float*)d_in[1];
    const float* m_all = (const float*)d_in[2];
    float* out = (float*)d_out;
    float* ws  = (float*)d_ws;

    size_t off = 0;
    float* bs_c = ws + off; off += (size_t)CH * LL;
    float* fs_c = ws + off; off += (size_t)CH * LL;
    float* ssq  = ws + off; off += LL;
    float* invn = ws + off; off += LL;
    float* mmv  = ws + off; off += LL;
    float* Mq   = ws + off; off += LL;
    float* Dq   = ws + off; off += LL;
    float* pmax = ws + off; off += (size_t)NCH2 * LL;
    float* psum = ws + off; off += (size_t)NCH2 * LL;
    float* bufA = ws + off; off += (size_t)LL * LL;   // D -> S1 -> Z0
    float* bufB = ws + off; off += (size_t)LL * LL;   // (splits) -> yi -> S2 -> Z1
    __hip_bfloat16* W2T   = (__hip_bfloat16*)(ws + off); off += (size_t)CKN * LL / 2;
    __hip_bfloat16* attnT = (__hip_bfloat16*)(ws + off); off += (size_t)LL * LL / 2;

    // split-bf16 operands for GEMM1, aliased into bufB (dead once gemm1 completes)
    __hip_bfloat16* bsT_hi = (__hip_bfloat16*)bufB;
    __hip_bfloat16* bsT_lo = bsT_hi + (size_t)LL * CH;
    __hip_bfloat16* fsT_hi = bsT_lo + (size_t)LL * CH;
    __hip_bfloat16* fsT_lo = fsT_hi + (size_t)LL * CH;

    for (int i = 0; i < NS; ++i) {
        const float* b  = b_all + (size_t)i * CH * HW * HW;
        const float* f  = f_all + (size_t)i * CH * HW * HW;
        const float* mk = m_all + (size_t)i * HW * HW;
        float* outp = out + (size_t)i * CH * HW * HW;

        hipMemsetAsync(ssq, 0, LL * sizeof(float), stream);
        k_stage    <<<dim3(9, CH), 256, 0, stream>>>(b, f, bs_c, fs_c);
        k_ssq      <<<dim3(9, 4), 256, 0, stream>>>(bs_c, ssq);
        k_norm_mm  <<<9, 256, 0, stream>>>(ssq, mk, invn, mmv);
        k_w2T      <<<dim3(9, CKN), 256, 0, stream>>>(b, W2T);
        k_split_T  <<<dim3(72, 4, 2), 256, 0, stream>>>(bs_c, fs_c, bsT_hi, bsT_lo, fsT_hi, fsT_lo);

        // GEMM1: D[p][q] = sum_c bs[p][c]*fs[q][c]  (split-bf16 MFMA) -> bufA
        gemm1_mfma <<<dim3(18, 18), 256, 0, stream>>>(bsT_hi, bsT_lo, fsT_hi, fsT_lo, bufA);
        // corr: D (bufA) -> yi (bufB, splits dead)
        k_corr     <<<dim3(9, LL), 256, 0, stream>>>(bufA, invn, bufB);
        // fuse1: yi (bufB) -> S1 (bufA, D dead)
        k_fuse1    <<<dim3(9, LL), 256, 0, stream>>>(bufB, bufA);
        // fuse2 + softmax partials: S1 (bufA) -> S2 (bufB, yi dead)
        k_fuse2_sm <<<dim3(9, NCH2), 256, 0, stream>>>(bufA, mmv, bufB, pmax, psum);

        k_sm2      <<<36, 256, 0, stream>>>(pmax, psum, Mq, Dq);
        k_sm3T     <<<dim3(72, 72), 256, 0, stream>>>(bufB, mmv, Mq, Dq, attnT);

        // GEMM2 (bf16 MFMA, split-K 2): Z0 -> bufA (S1 dead), Z1 -> bufB (S2 dead)
        gemm2_mfma <<<dim3(CKN / 128, LL / 128, 2), 256, 0, stream>>>(attnT, W2T, bufA, bufB, LL, CKN, LL);
        k_out      <<<dim3(36, CH), 256, 0, stream>>>(bufA, bufB, outp);
    }
}

// Round 6
// 763.091 us; speedup vs baseline: 1.4096x; 1.2607x over previous
//
#include <hip/hip_runtime.h>
#include <hip/hip_bf16.h>
#include <math.h>

#define NS   4      // batch
#define CH   128    // channels
#define HW   96     // full-res H=W
#define GS   48     // half-res grid side
#define LL   2304   // GS*GS
#define CKN  2048   // CH*16 (4x4 taps)
#define SCALE 10.0f
#define EPSSUM 0.1152f  // 1152 * 1e-4
#define PCH2 32     // softmax p-chunk
#define NCH2 72     // 2304/32
#define KH   1152   // GEMM2 split-K half

// per-sample strides (elements)
#define S_IN  ((size_t)CH * HW * HW)   // b / f / out
#define S_MK  ((size_t)HW * HW)        // mask
#define S_BS  ((size_t)CH * LL)        // bs_c / fs_c
#define S_PM  ((size_t)NCH2 * LL)      // pmax / psum
#define S_BUF ((size_t)LL * LL)        // bufA / bufB (fp32)
#define S_W2  ((size_t)CKN * LL)       // W2T (bf16 elems)
#define S_AT  ((size_t)LL * LL)        // attnT (bf16 elems)

typedef __attribute__((ext_vector_type(8))) short short8;
typedef __attribute__((ext_vector_type(4))) float float4v;

#define GLDS16(gptr, lptr) \
    __builtin_amdgcn_global_load_lds((const __attribute__((address_space(1))) void*)(gptr), \
        (__attribute__((address_space(3))) void*)(lptr), 16, 0, 0)

// ---------------- staging ----------------

__global__ __launch_bounds__(256) void k_stage(const float* __restrict__ b, const float* __restrict__ f,
                                               float* __restrict__ bs_c, float* __restrict__ fs_c) {
    int s = blockIdx.z;
    b += s * S_IN; f += s * S_IN; bs_c += s * S_BS; fs_c += s * S_BS;
    int c  = blockIdx.y;
    int rs = blockIdx.x * 256 + threadIdx.x;     // gridDim.x = 9
    int r = rs / GS, ss = rs % GS;
    int src = c * HW * HW + (2 * r) * HW + 2 * ss;
    bs_c[c * LL + rs] = b[src];
    fs_c[c * LL + rs] = f[src];
}

// partial ssq over 32 channels per block-row; ssq zeroed first (atomic accumulate)
__global__ __launch_bounds__(256) void k_ssq(const float* __restrict__ bs_c, float* __restrict__ ssq) {
    int s = blockIdx.z;
    bs_c += s * S_BS; ssq += (size_t)s * LL;
    int rs = blockIdx.x * 256 + threadIdx.x;
    int c0 = blockIdx.y * 32;
    float acc = 0.f;
    for (int c = c0; c < c0 + 32; ++c) { float v = bs_c[c * LL + rs]; acc += v * v; }
    atomicAdd(&ssq[rs], acc);
}

__global__ __launch_bounds__(256) void k_norm_mm(const float* __restrict__ ssq, const float* __restrict__ mk,
                                                 float* __restrict__ invn, float* __restrict__ mmv) {
    int sI = blockIdx.z;
    ssq += (size_t)sI * LL; mk += sI * S_MK; invn += (size_t)sI * LL; mmv += (size_t)sI * LL;
    int p = blockIdx.x * 256 + threadIdx.x;
    int ph = p / GS, pw = p % GS;
    float acc = EPSSUM;
    float msum = 0.f;
    for (int di = -1; di <= 1; ++di)
        for (int dj = -1; dj <= 1; ++dj) {
            int r = ph + di, s = pw + dj;
            if (r >= 0 && r < GS && s >= 0 && s < GS) {
                acc  += ssq[r * GS + s];
                msum += mk[(2 * r) * HW + 2 * s];
            }
        }
    invn[p] = 1.0f / sqrtf(acc);
    mmv[p]  = (msum / 9.0f == 1.0f) ? 1.0f : 0.0f;
}

// W2T[ck][p] = bf16( b[c, 2ph+dy-1, 2pw+dx-1] ), ck = c*16+dy*4+dx
__global__ __launch_bounds__(256) void k_w2T(const float* __restrict__ b, __hip_bfloat16* __restrict__ W2T) {
    int sI = blockIdx.z;
    b += sI * S_IN; W2T += sI * S_W2;
    int ck = blockIdx.y;
    int p  = blockIdx.x * 256 + threadIdx.x;     // gridDim.x = 9
    int c = ck >> 4, dy = (ck >> 2) & 3, dx = ck & 3;
    int ph = p / GS, pw = p % GS;
    int r = 2 * ph + dy - 1, s = 2 * pw + dx - 1;
    float v = 0.f;
    if (r >= 0 && r < HW && s >= 0 && s < HW) v = b[c * HW * HW + r * HW + s];
    W2T[(size_t)ck * LL + p] = __float2bfloat16(v);
}

// split fp32 [c][rs] -> transposed hi/lo bf16 [rs][c], into bufB_s scratch
__global__ __launch_bounds__(256) void k_split_T(const float* __restrict__ bs_c, const float* __restrict__ fs_c,
                                                 float* __restrict__ bufB) {
    __shared__ float tile[32][33];
    int z = blockIdx.z;
    int s = z >> 1, sel = z & 1;
    const float* X = (sel ? fs_c : bs_c) + s * S_BS;
    __hip_bfloat16* base = (__hip_bfloat16*)(bufB + s * S_BUF);
    __hip_bfloat16* hi = base + (size_t)sel * 2 * LL * CH;
    __hip_bfloat16* lo = hi + (size_t)LL * CH;
    int r0 = blockIdx.x * 32, c0 = blockIdx.y * 32;
    int tx = threadIdx.x & 31, ty = threadIdx.x >> 5;
#pragma unroll
    for (int j = 0; j < 4; ++j)
        tile[ty + 8 * j][tx] = X[(size_t)(c0 + ty + 8 * j) * LL + r0 + tx];
    __syncthreads();
#pragma unroll
    for (int j = 0; j < 4; ++j) {
        int rl = ty + 8 * j, cl = tx;
        float v = tile[cl][rl];
        __hip_bfloat16 h = __float2bfloat16(v);
        float resid = v - __bfloat162float(h);
        hi[(size_t)(r0 + rl) * CH + c0 + cl] = h;
        lo[(size_t)(r0 + rl) * CH + c0 + cl] = __float2bfloat16(resid);
    }
}

// ---------------- GEMM1 (split-bf16 MFMA): D = bs fs^T over channels ----------------
__global__ __launch_bounds__(256) void gemm1_mfma(const float* __restrict__ bufB, float* __restrict__ bufA) {
    __shared__ __hip_bfloat16 sAh[128 * 32];
    __shared__ __hip_bfloat16 sAl[128 * 32];
    __shared__ __hip_bfloat16 sBh[128 * 32];
    __shared__ __hip_bfloat16 sBl[128 * 32];
    int sI = blockIdx.z;
    const __hip_bfloat16* base = (const __hip_bfloat16*)(bufB + sI * S_BUF);
    const __hip_bfloat16* Ahi = base;
    const __hip_bfloat16* Alo = Ahi + (size_t)LL * CH;
    const __hip_bfloat16* Bhi = Alo + (size_t)LL * CH;
    const __hip_bfloat16* Blo = Bhi + (size_t)LL * CH;
    float* C = bufA + sI * S_BUF;

    int t = threadIdx.x, lane = t & 63, w = t >> 6;
    int wr = w >> 1, wc = w & 1;
    int m0 = blockIdx.y * 128, n0 = blockIdx.x * 128;

    float4v acc[4][4];
#pragma unroll
    for (int i = 0; i < 4; ++i)
#pragma unroll
        for (int j = 0; j < 4; ++j) acc[i][j] = (float4v){0.f, 0.f, 0.f, 0.f};

    for (int k0 = 0; k0 < 128; k0 += 32) {
#pragma unroll
        for (int it = 0; it < 2; ++it) {
            int chunk = it * 256 + w * 64 + lane;
            int row = chunk >> 2, ps = chunk & 3;
            int pd = ps ^ (row & 3);
            size_t ga = (size_t)(m0 + row) * 128 + k0 + pd * 8;
            size_t gb = (size_t)(n0 + row) * 128 + k0 + pd * 8;
            GLDS16(Ahi + ga, (char*)sAh + (size_t)chunk * 16);
            GLDS16(Alo + ga, (char*)sAl + (size_t)chunk * 16);
            GLDS16(Bhi + gb, (char*)sBh + (size_t)chunk * 16);
            GLDS16(Blo + gb, (char*)sBl + (size_t)chunk * 16);
        }
        __syncthreads();

        int lrow = lane & 15, part = lane >> 4;
        int sw = part ^ (lrow & 3);
        short8 ah[4], al[4], bh[4], bl[4];
#pragma unroll
        for (int i = 0; i < 4; ++i) {
            int slot = (wr * 64 + i * 16 + lrow) * 4 + sw;
            ah[i] = *reinterpret_cast<const short8*>(sAh + (size_t)slot * 8);
            al[i] = *reinterpret_cast<const short8*>(sAl + (size_t)slot * 8);
        }
#pragma unroll
        for (int j = 0; j < 4; ++j) {
            int slot = (wc * 64 + j * 16 + lrow) * 4 + sw;
            bh[j] = *reinterpret_cast<const short8*>(sBh + (size_t)slot * 8);
            bl[j] = *reinterpret_cast<const short8*>(sBl + (size_t)slot * 8);
        }
#pragma unroll
        for (int i = 0; i < 4; ++i)
#pragma unroll
            for (int j = 0; j < 4; ++j) {
                acc[i][j] = __builtin_amdgcn_mfma_f32_16x16x32_bf16(ah[i], bh[j], acc[i][j], 0, 0, 0);
                acc[i][j] = __builtin_amdgcn_mfma_f32_16x16x32_bf16(ah[i], bl[j], acc[i][j], 0, 0, 0);
                acc[i][j] = __builtin_amdgcn_mfma_f32_16x16x32_bf16(al[i], bh[j], acc[i][j], 0, 0, 0);
            }
        __syncthreads();
    }

    int col = lane & 15, rbase = (lane >> 4) * 4;
#pragma unroll
    for (int i = 0; i < 4; ++i)
#pragma unroll
        for (int j = 0; j < 4; ++j)
#pragma unroll
            for (int r = 0; r < 4; ++r) {
                int m = m0 + wr * 64 + i * 16 + rbase + r;
                int n = n0 + wc * 64 + j * 16 + col;
                C[(size_t)m * LL + n] = acc[i][j][r];
            }
}

// ---------------- GEMM2 (bf16 MFMA, split-K(2)) ----------------
__global__ __launch_bounds__(256) void gemm2_mfma(const __hip_bfloat16* __restrict__ attnT,
                                                  const __hip_bfloat16* __restrict__ W2T,
                                                  float* __restrict__ bufA, float* __restrict__ bufB) {
    __shared__ __hip_bfloat16 As[128 * 32];
    __shared__ __hip_bfloat16 Bs[128 * 32];
    int zz = blockIdx.z;
    int sI = zz >> 1, half = zz & 1;
    const __hip_bfloat16* A = attnT + sI * S_AT;       // [LL][LL]  (K = LL)
    const __hip_bfloat16* B = W2T + sI * S_W2;         // [CKN][LL]
    float* C = (half ? bufB : bufA) + sI * S_BUF;      // [LL][CKN]

    int t = threadIdx.x;
    int lane = t & 63, w = t >> 6;
    int wr = w >> 1, wc = w & 1;
    int m0 = blockIdx.y * 128, n0 = blockIdx.x * 128;

    float4v acc[4][4];
#pragma unroll
    for (int i = 0; i < 4; ++i)
#pragma unroll
        for (int j = 0; j < 4; ++j) acc[i][j] = (float4v){0.f, 0.f, 0.f, 0.f};

    for (int k0 = half * KH; k0 < half * KH + KH; k0 += 32) {
#pragma unroll
        for (int it = 0; it < 2; ++it) {
            int chunk = it * 256 + w * 64 + lane;
            int row = chunk >> 2, ps = chunk & 3;
            int pd = ps ^ (row & 3);
            const __hip_bfloat16* ga = A + (size_t)(m0 + row) * LL + k0 + pd * 8;
            const __hip_bfloat16* gb = B + (size_t)(n0 + row) * LL + k0 + pd * 8;
            GLDS16(ga, (char*)As + (size_t)chunk * 16);
            GLDS16(gb, (char*)Bs + (size_t)chunk * 16);
        }
        __syncthreads();

        int lrow = lane & 15, part = lane >> 4;
        int sw = part ^ (lrow & 3);
        short8 afrag[4], bfrag[4];
#pragma unroll
        for (int i = 0; i < 4; ++i) {
            int slot = (wr * 64 + i * 16 + lrow) * 4 + sw;
            afrag[i] = *reinterpret_cast<const short8*>(As + (size_t)slot * 8);
        }
#pragma unroll
        for (int j = 0; j < 4; ++j) {
            int slot = (wc * 64 + j * 16 + lrow) * 4 + sw;
            bfrag[j] = *reinterpret_cast<const short8*>(Bs + (size_t)slot * 8);
        }
#pragma unroll
        for (int i = 0; i < 4; ++i)
#pragma unroll
            for (int j = 0; j < 4; ++j)
                acc[i][j] = __builtin_amdgcn_mfma_f32_16x16x32_bf16(afrag[i], bfrag[j], acc[i][j], 0, 0, 0);
        __syncthreads();
    }

    int col = lane & 15, rbase = (lane >> 4) * 4;
#pragma unroll
    for (int i = 0; i < 4; ++i)
#pragma unroll
        for (int j = 0; j < 4; ++j)
#pragma unroll
            for (int r = 0; r < 4; ++r) {
                int m = m0 + wr * 64 + i * 16 + rbase + r;
                int n = n0 + wc * 64 + j * 16 + col;
                C[(size_t)m * CKN + n] = acc[i][j][r];
            }
}

// ---------------- correlation assembly + fuses ----------------

__global__ __launch_bounds__(256) void k_corr(const float* __restrict__ bufA, const float* __restrict__ invn,
                                              float* __restrict__ bufB) {
    int sI = blockIdx.z;
    const float* D = bufA + sI * S_BUF;
    float* yi = bufB + sI * S_BUF;
    invn += (size_t)sI * LL;
    int p = blockIdx.y;
    int q = blockIdx.x * 256 + threadIdx.x;
    int ph = p / GS, pw = p % GS, qh = q / GS, qw = q % GS;
    float s = 0.f;
#pragma unroll
    for (int di = -1; di <= 1; ++di) {
        int rp = ph + di, tq = qh + di;
        if (rp < 0 || rp >= GS || tq < 0 || tq >= GS) continue;
#pragma unroll
        for (int dj = -1; dj <= 1; ++dj) {
            int sp = pw + dj, uq = qw + dj;
            if (sp < 0 || sp >= GS || uq < 0 || uq >= GS) continue;
            s += D[(size_t)(rp * GS + sp) * LL + (tq * GS + uq)];
        }
    }
    yi[(size_t)p * LL + q] = invn[p] * s;
}

__global__ __launch_bounds__(256) void k_fuse1(const float* __restrict__ bufB, float* __restrict__ bufA) {
    int sI = blockIdx.z;
    const float* yi = bufB + sI * S_BUF;
    float* S1 = bufA + sI * S_BUF;
    int a = blockIdx.y;
    int bcol = blockIdx.x * 256 + threadIdx.x;
    float s = 0.f;
#pragma unroll
    for (int d = -1; d <= 1; ++d) {
        int aa = a + d, bb = bcol + d;
        if (aa >= 0 && aa < LL && bb >= 0 && bb < LL) s += yi[(size_t)aa * LL + bb];
    }
    S1[(size_t)a * LL + bcol] = s;
}

__device__ __forceinline__ int gmap(int x) { int hi = x / GS; int lo = x - hi * GS; return lo * GS + hi; }

// fuse2 + softmax partials
__global__ __launch_bounds__(256) void k_fuse2_sm(const float* __restrict__ bufA, const float* __restrict__ mmv,
                                                  float* __restrict__ bufB,
                                                  float* __restrict__ pmax, float* __restrict__ psum) {
    int sI = blockIdx.z;
    const float* S1 = bufA + sI * S_BUF;
    float* S2 = bufB + sI * S_BUF;
    mmv += (size_t)sI * LL; pmax += sI * S_PM; psum += sI * S_PM;
    int q = blockIdx.x * 256 + threadIdx.x;
    int qh = q / GS, qw = q % GS;
    int b0 = qw * GS + qh;
    int p0 = blockIdx.y * PCH2;
    float mx = -1e30f, sm = 0.f;
    for (int i = 0; i < PCH2; ++i) {
        int p = p0 + i;
        int ph = p / GS, pw = p % GS;
        int a0 = pw * GS + ph;
        float s = 0.f;
#pragma unroll
        for (int e = -1; e <= 1; ++e) {
            int ae = a0 + e, be = b0 + e;
            if (ae >= 0 && ae < LL && be >= 0 && be < LL)
                s += S1[(size_t)gmap(ae) * LL + gmap(be)];
        }
        S2[(size_t)p * LL + q] = s;
        float lg = (mmv[p] != 0.f) ? SCALE * s : 0.f;
        float nm = fmaxf(mx, lg);
        sm = sm * __expf(mx - nm) + __expf(lg - nm);
        mx = nm;
    }
    pmax[blockIdx.y * LL + q] = mx;
    psum[blockIdx.y * LL + q] = sm;
}

// final softmax max/denominator: 4-way tree over 72 chunks, 64 q per block
__global__ __launch_bounds__(256) void k_sm2(const float* __restrict__ pmax, const float* __restrict__ psum,
                                             float* __restrict__ Mq, float* __restrict__ Dq) {
    __shared__ float red[4][64];
    int sI = blockIdx.z;
    pmax += sI * S_PM; psum += sI * S_PM; Mq += (size_t)sI * LL; Dq += (size_t)sI * LL;
    int t = threadIdx.x;
    int ql = t & 63, g = t >> 6;
    int q = blockIdx.x * 64 + ql;
    float mx = -1e30f;
    for (int ch = g * 18; ch < g * 18 + 18; ++ch) mx = fmaxf(mx, pmax[(size_t)ch * LL + q]);
    red[g][ql] = mx;
    __syncthreads();
    float mall = fmaxf(fmaxf(red[0][ql], red[1][ql]), fmaxf(red[2][ql], red[3][ql]));
    float sm = 0.f;
    for (int ch = g * 18; ch < g * 18 + 18; ++ch)
        sm += psum[(size_t)ch * LL + q] * __expf(pmax[(size_t)ch * LL + q] - mall);
    __syncthreads();
    red[g][ql] = sm;
    __syncthreads();
    if (g == 0) {
        Mq[q] = mall;
        Dq[q] = (red[0][ql] + red[1][ql]) + (red[2][ql] + red[3][ql]);
    }
}

// attnT[q][p] = bf16( mmv[p] * exp(10*S2[p][q] - Mq[q]) / Dq[q] ) via 32x32 LDS transpose
__global__ __launch_bounds__(256) void k_sm3T(const float* __restrict__ bufB, const float* __restrict__ mmv,
                                              const float* __restrict__ Mq, const float* __restrict__ Dq,
                                              __hip_bfloat16* __restrict__ attnT) {
    __shared__ float tile[32][33];
    int sI = blockIdx.z;
    const float* S2 = bufB + sI * S_BUF;
    mmv += (size_t)sI * LL; Mq += (size_t)sI * LL; Dq += (size_t)sI * LL; attnT += sI * S_AT;
    int tx = threadIdx.x & 31, ty = threadIdx.x >> 5;
    int p0 = blockIdx.y * 32, q0 = blockIdx.x * 32;
    int q = q0 + tx;
    float mq = Mq[q], dq = Dq[q];
#pragma unroll
    for (int j = 0; j < 4; ++j) {
        int p = p0 + ty + 8 * j;
        float v = S2[(size_t)p * LL + q];
        float attn = (mmv[p] != 0.f) ? __expf(SCALE * v - mq) / dq : 0.f;
        tile[ty + 8 * j][tx] = attn;
    }
    __syncthreads();
#pragma unroll
    for (int j = 0; j < 4; ++j) {
        int qq = q0 + ty + 8 * j;
        attnT[(size_t)qq * LL + p0 + tx] = __float2bfloat16(tile[tx][ty + 8 * j]);
    }
}

// ---------------- output assembly (sums split-K halves) ----------------
__global__ __launch_bounds__(256) void k_out(const float* __restrict__ bufA, const float* __restrict__ bufB,
                                             float* __restrict__ out) {
    int sI = blockIdx.z;
    const float* Z0 = bufA + sI * S_BUF;
    const float* Z1 = bufB + sI * S_BUF;
    out += sI * S_IN;
    int c  = blockIdx.y;
    int yx = blockIdx.x * 256 + threadIdx.x;     // gridDim.x = 36
    int y = yx / HW, x = yx % HW;
    int u = y >> 1, a = y & 1, v = x >> 1, w = x & 1;
    int qh1 = u + a - 1, qh2 = u + a, qw1 = v + w - 1, qw2 = v + w;
    int cb = c * 16;
    float s = 0.f;
    if (qh1 >= 0) {
        if (qw1 >= 0) { size_t i0 = (size_t)(qh1 * GS + qw1) * CKN + cb + (3 - a) * 4 + (3 - w); s += Z0[i0] + Z1[i0]; }
        if (qw2 < GS) { size_t i1 = (size_t)(qh1 * GS + qw2) * CKN + cb + (3 - a) * 4 + (1 - w); s += Z0[i1] + Z1[i1]; }
    }
    if (qh2 < GS) {
        if (qw1 >= 0) { size_t i2 = (size_t)(qh2 * GS + qw1) * CKN + cb + (1 - a) * 4 + (3 - w); s += Z0[i2] + Z1[i2]; }
        if (qw2 < GS) { size_t i3 = (size_t)(qh2 * GS + qw2) * CKN + cb + (1 - a) * 4 + (1 - w); s += Z0[i3] + Z1[i3]; }
    }
    out[(size_t)c * HW * HW + yx] = 0.25f * s;
}

// ---------------- launch ----------------

extern "C" void kernel_launch(void* const* d_in, const int* in_sizes, int n_in,
                              void* d_out, int out_size, void* d_ws, size_t ws_size,
                              hipStream_t stream) {
    const float* b_all = (const float*)d_in[0];
    const float* f_all = (const float*)d_in[1];
    const float* m_all = (const float*)d_in[2];
    float* out = (float*)d_out;
    float* ws  = (float*)d_ws;

    // per-sample workspace (floats): 2*S_BS + 5*LL + 2*S_PM + 2*S_BUF + S_W2/2 + S_AT/2
    const size_t perF = 2 * S_BS + 5 * (size_t)LL + 2 * S_PM + 2 * S_BUF + S_W2 / 2 + S_AT / 2;
    const size_t perB = perF * sizeof(float);
    int nb = (ws_size >= NS * perB) ? NS : ((ws_size >= 2 * perB) ? 2 : 1);

    // layout: each array replicated nb times contiguously
    size_t off = 0;
    float* bs_c = ws + off; off += nb * S_BS;
    float* fs_c = ws + off; off += nb * S_BS;
    float* ssq  = ws + off; off += nb * (size_t)LL;
    float* invn = ws + off; off += nb * (size_t)LL;
    float* mmv  = ws + off; off += nb * (size_t)LL;
    float* Mq   = ws + off; off += nb * (size_t)LL;
    float* Dq   = ws + off; off += nb * (size_t)LL;
    float* pmax = ws + off; off += nb * S_PM;
    float* psum = ws + off; off += nb * S_PM;
    float* bufA = ws + off; off += nb * S_BUF;   // D -> S1 -> Z0
    float* bufB = ws + off; off += nb * S_BUF;   // (splits) -> yi -> S2 -> Z1
    __hip_bfloat16* W2T   = (__hip_bfloat16*)(ws + off); off += nb * S_W2 / 2;
    __hip_bfloat16* attnT = (__hip_bfloat16*)(ws + off); off += nb * S_AT / 2;

    for (int s0 = 0; s0 < NS; s0 += nb) {
        const float* b  = b_all + s0 * S_IN;
        const float* f  = f_all + s0 * S_IN;
        const float* mk = m_all + s0 * S_MK;
        float* outp = out + s0 * S_IN;

        hipMemsetAsync(ssq, 0, nb * LL * sizeof(float), stream);
        k_stage    <<<dim3(9, CH, nb), 256, 0, stream>>>(b, f, bs_c, fs_c);
        k_ssq      <<<dim3(9, 4, nb), 256, 0, stream>>>(bs_c, ssq);
        k_norm_mm  <<<dim3(9, 1, nb), 256, 0, stream>>>(ssq, mk, invn, mmv);
        k_w2T      <<<dim3(9, CKN, nb), 256, 0, stream>>>(b, W2T);
        k_split_T  <<<dim3(72, 4, 2 * nb), 256, 0, stream>>>(bs_c, fs_c, bufB);

        gemm1_mfma <<<dim3(18, 18, nb), 256, 0, stream>>>(bufB, bufA);
        k_corr     <<<dim3(9, LL, nb), 256, 0, stream>>>(bufA, invn, bufB);
        k_fuse1    <<<dim3(9, LL, nb), 256, 0, stream>>>(bufB, bufA);
        k_fuse2_sm <<<dim3(9, NCH2, nb), 256, 0, stream>>>(bufA, mmv, bufB, pmax, psum);

        k_sm2      <<<dim3(36, 1, nb), 256, 0, stream>>>(pmax, psum, Mq, Dq);
        k_sm3T     <<<dim3(72, 72, nb), 256, 0, stream>>>(bufB, mmv, Mq, Dq, attnT);

        gemm2_mfma <<<dim3(CKN / 128, LL / 128, 2 * nb), 256, 0, stream>>>(attnT, W2T, bufA, bufB);
        k_out      <<<dim3(36, CH, nb), 256, 0, stream>>>(bufA, bufB, outp);
    }
}

// Round 7
// 667.951 us; speedup vs baseline: 1.6104x; 1.1424x over previous
//
#include <hip/hip_runtime.h>
#include <hip/hip_bf16.h>
#include <math.h>

#define NS   4      // batch
#define CH   128    // channels
#define HW   96     // full-res H=W
#define GS   48     // half-res grid side
#define LL   2304   // GS*GS
#define CKN  2048   // CH*16 (4x4 taps)
#define SCALE 10.0f
#define EPSSUM 0.1152f  // 1152 * 1e-4
#define PCH2 32     // softmax p-chunk
#define NCH2 72     // 2304/32

// per-sample strides (elements)
#define S_IN  ((size_t)CH * HW * HW)   // b / f / out
#define S_MK  ((size_t)HW * HW)        // mask
#define S_BS  ((size_t)CH * LL)        // bs_c / fs_c
#define S_PM  ((size_t)NCH2 * LL)      // pmax / psum
#define S_BUF ((size_t)LL * LL)        // bufA / bufB (fp32)
#define S_W2  ((size_t)CKN * LL)       // W2T (bf16 elems)
#define S_AT  ((size_t)LL * LL)        // attnT (bf16 elems)

typedef __attribute__((ext_vector_type(8))) short short8;
typedef __attribute__((ext_vector_type(4))) float float4v;

#define GLDS16(gptr, lptr) \
    __builtin_amdgcn_global_load_lds((const __attribute__((address_space(1))) void*)(gptr), \
        (__attribute__((address_space(3))) void*)(lptr), 16, 0, 0)

// ---------------- staging ----------------

__global__ __launch_bounds__(256) void k_stage(const float* __restrict__ b, const float* __restrict__ f,
                                               float* __restrict__ bs_c, float* __restrict__ fs_c) {
    int s = blockIdx.z;
    b += s * S_IN; f += s * S_IN; bs_c += s * S_BS; fs_c += s * S_BS;
    int c  = blockIdx.y;
    int rs = blockIdx.x * 256 + threadIdx.x;     // gridDim.x = 9
    int r = rs / GS, ss = rs % GS;
    int src = c * HW * HW + (2 * r) * HW + 2 * ss;
    bs_c[c * LL + rs] = b[src];
    fs_c[c * LL + rs] = f[src];
}

// partial ssq over 32 channels per block-row; ssq zeroed first (atomic accumulate)
__global__ __launch_bounds__(256) void k_ssq(const float* __restrict__ bs_c, float* __restrict__ ssq) {
    int s = blockIdx.z;
    bs_c += s * S_BS; ssq += (size_t)s * LL;
    int rs = blockIdx.x * 256 + threadIdx.x;
    int c0 = blockIdx.y * 32;
    float acc = 0.f;
    for (int c = c0; c < c0 + 32; ++c) { float v = bs_c[c * LL + rs]; acc += v * v; }
    atomicAdd(&ssq[rs], acc);
}

__global__ __launch_bounds__(256) void k_norm_mm(const float* __restrict__ ssq, const float* __restrict__ mk,
                                                 float* __restrict__ invn, float* __restrict__ mmv) {
    int sI = blockIdx.z;
    ssq += (size_t)sI * LL; mk += sI * S_MK; invn += (size_t)sI * LL; mmv += (size_t)sI * LL;
    int p = blockIdx.x * 256 + threadIdx.x;
    int ph = p / GS, pw = p % GS;
    float acc = EPSSUM;
    float msum = 0.f;
    for (int di = -1; di <= 1; ++di)
        for (int dj = -1; dj <= 1; ++dj) {
            int r = ph + di, s = pw + dj;
            if (r >= 0 && r < GS && s >= 0 && s < GS) {
                acc  += ssq[r * GS + s];
                msum += mk[(2 * r) * HW + 2 * s];
            }
        }
    invn[p] = 1.0f / sqrtf(acc);
    mmv[p]  = (msum / 9.0f == 1.0f) ? 1.0f : 0.0f;
}

// W2T[ck][p] = bf16( b[c, 2ph+dy-1, 2pw+dx-1] ), ck = c*16+dy*4+dx
__global__ __launch_bounds__(256) void k_w2T(const float* __restrict__ b, __hip_bfloat16* __restrict__ W2T) {
    int sI = blockIdx.z;
    b += sI * S_IN; W2T += sI * S_W2;
    int ck = blockIdx.y;
    int p  = blockIdx.x * 256 + threadIdx.x;     // gridDim.x = 9
    int c = ck >> 4, dy = (ck >> 2) & 3, dx = ck & 3;
    int ph = p / GS, pw = p % GS;
    int r = 2 * ph + dy - 1, s = 2 * pw + dx - 1;
    float v = 0.f;
    if (r >= 0 && r < HW && s >= 0 && s < HW) v = b[c * HW * HW + r * HW + s];
    W2T[(size_t)ck * LL + p] = __float2bfloat16(v);
}

// split fp32 [c][rs] -> transposed hi/lo bf16 [rs][c], into bufB scratch
__global__ __launch_bounds__(256) void k_split_T(const float* __restrict__ bs_c, const float* __restrict__ fs_c,
                                                 float* __restrict__ bufB) {
    __shared__ float tile[32][33];
    int z = blockIdx.z;
    int s = z >> 1, sel = z & 1;
    const float* X = (sel ? fs_c : bs_c) + s * S_BS;
    __hip_bfloat16* base = (__hip_bfloat16*)(bufB + s * S_BUF);
    __hip_bfloat16* hi = base + (size_t)sel * 2 * LL * CH;
    __hip_bfloat16* lo = hi + (size_t)LL * CH;
    int r0 = blockIdx.x * 32, c0 = blockIdx.y * 32;
    int tx = threadIdx.x & 31, ty = threadIdx.x >> 5;
#pragma unroll
    for (int j = 0; j < 4; ++j)
        tile[ty + 8 * j][tx] = X[(size_t)(c0 + ty + 8 * j) * LL + r0 + tx];
    __syncthreads();
#pragma unroll
    for (int j = 0; j < 4; ++j) {
        int rl = ty + 8 * j, cl = tx;
        float v = tile[cl][rl];
        __hip_bfloat16 h = __float2bfloat16(v);
        float resid = v - __bfloat162float(h);
        hi[(size_t)(r0 + rl) * CH + c0 + cl] = h;
        lo[(size_t)(r0 + rl) * CH + c0 + cl] = __float2bfloat16(resid);
    }
}

// ---------------- GEMM1 (split-bf16 MFMA): D = bs fs^T over channels ----------------
__global__ __launch_bounds__(256) void gemm1_mfma(const float* __restrict__ bufB, float* __restrict__ bufA) {
    __shared__ __hip_bfloat16 sAh[128 * 32];
    __shared__ __hip_bfloat16 sAl[128 * 32];
    __shared__ __hip_bfloat16 sBh[128 * 32];
    __shared__ __hip_bfloat16 sBl[128 * 32];
    int sI = blockIdx.z;
    const __hip_bfloat16* base = (const __hip_bfloat16*)(bufB + sI * S_BUF);
    const __hip_bfloat16* Ahi = base;
    const __hip_bfloat16* Alo = Ahi + (size_t)LL * CH;
    const __hip_bfloat16* Bhi = Alo + (size_t)LL * CH;
    const __hip_bfloat16* Blo = Bhi + (size_t)LL * CH;
    float* C = bufA + sI * S_BUF;

    int t = threadIdx.x, lane = t & 63, w = t >> 6;
    int wr = w >> 1, wc = w & 1;
    int m0 = blockIdx.y * 128, n0 = blockIdx.x * 128;

    float4v acc[4][4];
#pragma unroll
    for (int i = 0; i < 4; ++i)
#pragma unroll
        for (int j = 0; j < 4; ++j) acc[i][j] = (float4v){0.f, 0.f, 0.f, 0.f};

    for (int k0 = 0; k0 < 128; k0 += 32) {
#pragma unroll
        for (int it = 0; it < 2; ++it) {
            int chunk = it * 256 + w * 64 + lane;
            int row = chunk >> 2, ps = chunk & 3;
            int pd = ps ^ (row & 3);
            size_t ga = (size_t)(m0 + row) * 128 + k0 + pd * 8;
            size_t gb = (size_t)(n0 + row) * 128 + k0 + pd * 8;
            GLDS16(Ahi + ga, (char*)sAh + (size_t)chunk * 16);
            GLDS16(Alo + ga, (char*)sAl + (size_t)chunk * 16);
            GLDS16(Bhi + gb, (char*)sBh + (size_t)chunk * 16);
            GLDS16(Blo + gb, (char*)sBl + (size_t)chunk * 16);
        }
        __syncthreads();

        int lrow = lane & 15, part = lane >> 4;
        int sw = part ^ (lrow & 3);
        short8 ah[4], al[4], bh[4], bl[4];
#pragma unroll
        for (int i = 0; i < 4; ++i) {
            int slot = (wr * 64 + i * 16 + lrow) * 4 + sw;
            ah[i] = *reinterpret_cast<const short8*>(sAh + (size_t)slot * 8);
            al[i] = *reinterpret_cast<const short8*>(sAl + (size_t)slot * 8);
        }
#pragma unroll
        for (int j = 0; j < 4; ++j) {
            int slot = (wc * 64 + j * 16 + lrow) * 4 + sw;
            bh[j] = *reinterpret_cast<const short8*>(sBh + (size_t)slot * 8);
            bl[j] = *reinterpret_cast<const short8*>(sBl + (size_t)slot * 8);
        }
#pragma unroll
        for (int i = 0; i < 4; ++i)
#pragma unroll
            for (int j = 0; j < 4; ++j) {
                acc[i][j] = __builtin_amdgcn_mfma_f32_16x16x32_bf16(ah[i], bh[j], acc[i][j], 0, 0, 0);
                acc[i][j] = __builtin_amdgcn_mfma_f32_16x16x32_bf16(ah[i], bl[j], acc[i][j], 0, 0, 0);
                acc[i][j] = __builtin_amdgcn_mfma_f32_16x16x32_bf16(al[i], bh[j], acc[i][j], 0, 0, 0);
            }
        __syncthreads();
    }

    int col = lane & 15, rbase = (lane >> 4) * 4;
#pragma unroll
    for (int i = 0; i < 4; ++i)
#pragma unroll
        for (int j = 0; j < 4; ++j)
#pragma unroll
            for (int r = 0; r < 4; ++r) {
                int m = m0 + wr * 64 + i * 16 + rbase + r;
                int n = n0 + wc * 64 + j * 16 + col;
                C[(size_t)m * LL + n] = acc[i][j][r];
            }
}

// ---------------- GEMM2 (bf16 MFMA, no split-K, bf16 output) ----------------
// Zb[q][ck] = bf16( sum_p attnT[q][p] * W2T[ck][p] ), K = LL = 2304.
__global__ __launch_bounds__(256) void gemm2_mfma(const __hip_bfloat16* __restrict__ attnT,
                                                  const __hip_bfloat16* __restrict__ W2T,
                                                  float* __restrict__ bufB) {
    __shared__ __hip_bfloat16 As[128 * 32];
    __shared__ __hip_bfloat16 Bs[128 * 32];
    int sI = blockIdx.z;
    const __hip_bfloat16* A = attnT + sI * S_AT;       // [LL][LL]
    const __hip_bfloat16* B = W2T + sI * S_W2;         // [CKN][LL]
    __hip_bfloat16* C = (__hip_bfloat16*)(bufB + sI * S_BUF);   // Zb [LL][CKN]

    int t = threadIdx.x;
    int lane = t & 63, w = t >> 6;
    int wr = w >> 1, wc = w & 1;
    int m0 = blockIdx.y * 128, n0 = blockIdx.x * 128;

    float4v acc[4][4];
#pragma unroll
    for (int i = 0; i < 4; ++i)
#pragma unroll
        for (int j = 0; j < 4; ++j) acc[i][j] = (float4v){0.f, 0.f, 0.f, 0.f};

    for (int k0 = 0; k0 < LL; k0 += 32) {
#pragma unroll
        for (int it = 0; it < 2; ++it) {
            int chunk = it * 256 + w * 64 + lane;
            int row = chunk >> 2, ps = chunk & 3;
            int pd = ps ^ (row & 3);
            const __hip_bfloat16* ga = A + (size_t)(m0 + row) * LL + k0 + pd * 8;
            const __hip_bfloat16* gb = B + (size_t)(n0 + row) * LL + k0 + pd * 8;
            GLDS16(ga, (char*)As + (size_t)chunk * 16);
            GLDS16(gb, (char*)Bs + (size_t)chunk * 16);
        }
        __syncthreads();

        int lrow = lane & 15, part = lane >> 4;
        int sw = part ^ (lrow & 3);
        short8 afrag[4], bfrag[4];
#pragma unroll
        for (int i = 0; i < 4; ++i) {
            int slot = (wr * 64 + i * 16 + lrow) * 4 + sw;
            afrag[i] = *reinterpret_cast<const short8*>(As + (size_t)slot * 8);
        }
#pragma unroll
        for (int j = 0; j < 4; ++j) {
            int slot = (wc * 64 + j * 16 + lrow) * 4 + sw;
            bfrag[j] = *reinterpret_cast<const short8*>(Bs + (size_t)slot * 8);
        }
#pragma unroll
        for (int i = 0; i < 4; ++i)
#pragma unroll
            for (int j = 0; j < 4; ++j)
                acc[i][j] = __builtin_amdgcn_mfma_f32_16x16x32_bf16(afrag[i], bfrag[j], acc[i][j], 0, 0, 0);
        __syncthreads();
    }

    int col = lane & 15, rbase = (lane >> 4) * 4;
#pragma unroll
    for (int i = 0; i < 4; ++i)
#pragma unroll
        for (int j = 0; j < 4; ++j)
#pragma unroll
            for (int r = 0; r < 4; ++r) {
                int m = m0 + wr * 64 + i * 16 + rbase + r;
                int n = n0 + wc * 64 + j * 16 + col;
                C[(size_t)m * CKN + n] = __float2bfloat16(acc[i][j][r]);
            }
}

// ---------------- correlation assembly ----------------

__global__ __launch_bounds__(256) void k_corr(const float* __restrict__ bufA, const float* __restrict__ invn,
                                              float* __restrict__ bufB) {
    int sI = blockIdx.z;
    const float* D = bufA + sI * S_BUF;
    float* yi = bufB + sI * S_BUF;
    invn += (size_t)sI * LL;
    int p = blockIdx.y;
    int q = blockIdx.x * 256 + threadIdx.x;
    int ph = p / GS, pw = p % GS, qh = q / GS, qw = q % GS;
    float s = 0.f;
#pragma unroll
    for (int di = -1; di <= 1; ++di) {
        int rp = ph + di, tq = qh + di;
        if (rp < 0 || rp >= GS || tq < 0 || tq >= GS) continue;
#pragma unroll
        for (int dj = -1; dj <= 1; ++dj) {
            int sp = pw + dj, uq = qw + dj;
            if (sp < 0 || sp >= GS || uq < 0 || uq >= GS) continue;
            s += D[(size_t)(rp * GS + sp) * LL + (tq * GS + uq)];
        }
    }
    yi[(size_t)p * LL + q] = invn[p] * s;
}

__device__ __forceinline__ int gmap(int x) { int hi = x / GS; int lo = x - hi * GS; return lo * GS + hi; }

// fused fuse1+fuse2 + softmax partials:
// S2[p][q] = sum_{e: 0<=a0+e<LL} sum_{d: 0<=gmap(a0+e)+d<LL, 0<=gmap(b0+e)+d<LL}
//              yi[gmap(a0+e)+d][gmap(b0+e)+d]
// Rows are wave-uniform (p uniform per block) — k_corr's proven access structure.
__global__ __launch_bounds__(256) void k_fuse12_sm(const float* __restrict__ bufB, const float* __restrict__ mmv,
                                                   float* __restrict__ bufA,
                                                   float* __restrict__ pmax, float* __restrict__ psum) {
    int sI = blockIdx.z;
    const float* yi = bufB + sI * S_BUF;
    float* S2 = bufA + sI * S_BUF;
    mmv += (size_t)sI * LL; pmax += sI * S_PM; psum += sI * S_PM;
    int q = blockIdx.x * 256 + threadIdx.x;
    int qh = q / GS, qw = q % GS;
    int b0 = qw * GS + qh;
    // per-lane column bases for e = -1,0,1
    int Bc[3]; bool Bv[3];
#pragma unroll
    for (int e = 0; e < 3; ++e) {
        int be = b0 + e - 1;
        Bv[e] = (be >= 0 && be < LL);
        Bc[e] = Bv[e] ? gmap(be) : 0;
    }
    int p0 = blockIdx.y * PCH2;
    float mx = -1e30f, sm = 0.f;
    for (int i = 0; i < PCH2; ++i) {
        int p = p0 + i;
        int ph = p / GS, pw = p % GS;
        int a0 = pw * GS + ph;
        float s = 0.f;
#pragma unroll
        for (int e = 0; e < 3; ++e) {
            int ae = a0 + e - 1;
            if (ae < 0 || ae >= LL) continue;            // uniform
            int Ar = gmap(ae);                           // uniform
#pragma unroll
            for (int d = -1; d <= 1; ++d) {
                int aa = Ar + d;
                if (aa < 0 || aa >= LL) continue;        // uniform
                int bb = Bc[e] + d;                      // per-lane
                bool ok = Bv[e] && bb >= 0 && bb < LL;
                if (ok) s += yi[(size_t)aa * LL + bb];
            }
        }
        S2[(size_t)p * LL + q] = s;
        float lg = (mmv[p] != 0.f) ? SCALE * s : 0.f;
        float nm = fmaxf(mx, lg);
        sm = sm * __expf(mx - nm) + __expf(lg - nm);
        mx = nm;
    }
    pmax[blockIdx.y * LL + q] = mx;
    psum[blockIdx.y * LL + q] = sm;
}

// final softmax max/denominator: 4-way tree over 72 chunks, 64 q per block
__global__ __launch_bounds__(256) void k_sm2(const float* __restrict__ pmax, const float* __restrict__ psum,
                                             float* __restrict__ Mq, float* __restrict__ Dq) {
    __shared__ float red[4][64];
    int sI = blockIdx.z;
    pmax += sI * S_PM; psum += sI * S_PM; Mq += (size_t)sI * LL; Dq += (size_t)sI * LL;
    int t = threadIdx.x;
    int ql = t & 63, g = t >> 6;
    int q = blockIdx.x * 64 + ql;
    float mx = -1e30f;
    for (int ch = g * 18; ch < g * 18 + 18; ++ch) mx = fmaxf(mx, pmax[(size_t)ch * LL + q]);
    red[g][ql] = mx;
    __syncthreads();
    float mall = fmaxf(fmaxf(red[0][ql], red[1][ql]), fmaxf(red[2][ql], red[3][ql]));
    float sm = 0.f;
    for (int ch = g * 18; ch < g * 18 + 18; ++ch)
        sm += psum[(size_t)ch * LL + q] * __expf(pmax[(size_t)ch * LL + q] - mall);
    __syncthreads();
    red[g][ql] = sm;
    __syncthreads();
    if (g == 0) {
        Mq[q] = mall;
        Dq[q] = (red[0][ql] + red[1][ql]) + (red[2][ql] + red[3][ql]);
    }
}

// attnT[q][p] = bf16( mmv[p] * exp(10*S2[p][q] - Mq[q]) / Dq[q] ) via 32x32 LDS transpose
__global__ __launch_bounds__(256) void k_sm3T(const float* __restrict__ bufA, const float* __restrict__ mmv,
                                              const float* __restrict__ Mq, const float* __restrict__ Dq,
                                              __hip_bfloat16* __restrict__ attnT) {
    __shared__ float tile[32][33];
    int sI = blockIdx.z;
    const float* S2 = bufA + sI * S_BUF;
    mmv += (size_t)sI * LL; Mq += (size_t)sI * LL; Dq += (size_t)sI * LL; attnT += sI * S_AT;
    int tx = threadIdx.x & 31, ty = threadIdx.x >> 5;
    int p0 = blockIdx.y * 32, q0 = blockIdx.x * 32;
    int q = q0 + tx;
    float mq = Mq[q], dq = Dq[q];
#pragma unroll
    for (int j = 0; j < 4; ++j) {
        int p = p0 + ty + 8 * j;
        float v = S2[(size_t)p * LL + q];
        float attn = (mmv[p] != 0.f) ? __expf(SCALE * v - mq) / dq : 0.f;
        tile[ty + 8 * j][tx] = attn;
    }
    __syncthreads();
#pragma unroll
    for (int j = 0; j < 4; ++j) {
        int qq = q0 + ty + 8 * j;
        attnT[(size_t)qq * LL + p0 + tx] = __float2bfloat16(tile[tx][ty + 8 * j]);
    }
}

// ---------------- output assembly (reads bf16 Z) ----------------
__global__ __launch_bounds__(256) void k_out(const float* __restrict__ bufB, float* __restrict__ out) {
    int sI = blockIdx.z;
    const __hip_bfloat16* Z = (const __hip_bfloat16*)(bufB + sI * S_BUF);
    out += sI * S_IN;
    int c  = blockIdx.y;
    int yx = blockIdx.x * 256 + threadIdx.x;     // gridDim.x = 36
    int y = yx / HW, x = yx % HW;
    int u = y >> 1, a = y & 1, v = x >> 1, w = x & 1;
    int qh1 = u + a - 1, qh2 = u + a, qw1 = v + w - 1, qw2 = v + w;
    int cb = c * 16;
    float s = 0.f;
    if (qh1 >= 0) {
        if (qw1 >= 0)  s += __bfloat162float(Z[(size_t)(qh1 * GS + qw1) * CKN + cb + (3 - a) * 4 + (3 - w)]);
        if (qw2 < GS)  s += __bfloat162float(Z[(size_t)(qh1 * GS + qw2) * CKN + cb + (3 - a) * 4 + (1 - w)]);
    }
    if (qh2 < GS) {
        if (qw1 >= 0)  s += __bfloat162float(Z[(size_t)(qh2 * GS + qw1) * CKN + cb + (1 - a) * 4 + (3 - w)]);
        if (qw2 < GS)  s += __bfloat162float(Z[(size_t)(qh2 * GS + qw2) * CKN + cb + (1 - a) * 4 + (1 - w)]);
    }
    out[(size_t)c * HW * HW + yx] = 0.25f * s;
}

// ---------------- launch ----------------

extern "C" void kernel_launch(void* const* d_in, const int* in_sizes, int n_in,
                              void* d_out, int out_size, void* d_ws, size_t ws_size,
                              hipStream_t stream) {
    const float* b_all = (const float*)d_in[0];
    const float* f_all = (const float*)d_in[1];
    const float* m_all = (const float*)d_in[2];
    float* out = (float*)d_out;
    float* ws  = (float*)d_ws;

    const size_t perF = 2 * S_BS + 5 * (size_t)LL + 2 * S_PM + 2 * S_BUF + S_W2 / 2 + S_AT / 2;
    const size_t perB = perF * sizeof(float);
    int nb = (ws_size >= NS * perB) ? NS : ((ws_size >= 2 * perB) ? 2 : 1);

    size_t off = 0;
    float* bs_c = ws + off; off += nb * S_BS;
    float* fs_c = ws + off; off += nb * S_BS;
    float* ssq  = ws + off; off += nb * (size_t)LL;
    float* invn = ws + off; off += nb * (size_t)LL;
    float* mmv  = ws + off; off += nb * (size_t)LL;
    float* Mq   = ws + off; off += nb * (size_t)LL;
    float* Dq   = ws + off; off += nb * (size_t)LL;
    float* pmax = ws + off; off += nb * S_PM;
    float* psum = ws + off; off += nb * S_PM;
    float* bufA = ws + off; off += nb * S_BUF;   // D -> S2
    float* bufB = ws + off; off += nb * S_BUF;   // (splits) -> yi -> Zb(bf16)
    __hip_bfloat16* W2T   = (__hip_bfloat16*)(ws + off); off += nb * S_W2 / 2;
    __hip_bfloat16* attnT = (__hip_bfloat16*)(ws + off); off += nb * S_AT / 2;

    for (int s0 = 0; s0 < NS; s0 += nb) {
        const float* b  = b_all + s0 * S_IN;
        const float* f  = f_all + s0 * S_IN;
        const float* mk = m_all + s0 * S_MK;
        float* outp = out + s0 * S_IN;

        hipMemsetAsync(ssq, 0, nb * LL * sizeof(float), stream);
        k_stage    <<<dim3(9, CH, nb), 256, 0, stream>>>(b, f, bs_c, fs_c);
        k_ssq      <<<dim3(9, 4, nb), 256, 0, stream>>>(bs_c, ssq);
        k_norm_mm  <<<dim3(9, 1, nb), 256, 0, stream>>>(ssq, mk, invn, mmv);
        k_w2T      <<<dim3(9, CKN, nb), 256, 0, stream>>>(b, W2T);
        k_split_T  <<<dim3(72, 4, 2 * nb), 256, 0, stream>>>(bs_c, fs_c, bufB);

        gemm1_mfma <<<dim3(18, 18, nb), 256, 0, stream>>>(bufB, bufA);
        k_corr     <<<dim3(9, LL, nb), 256, 0, stream>>>(bufA, invn, bufB);
        k_fuse12_sm<<<dim3(9, NCH2, nb), 256, 0, stream>>>(bufB, mmv, bufA, pmax, psum);

        k_sm2      <<<dim3(36, 1, nb), 256, 0, stream>>>(pmax, psum, Mq, Dq);
        k_sm3T     <<<dim3(72, 72, nb), 256, 0, stream>>>(bufA, mmv, Mq, Dq, attnT);

        gemm2_mfma <<<dim3(CKN / 128, LL / 128, nb), 256, 0, stream>>>(attnT, W2T, bufB);
        k_out      <<<dim3(36, CH, nb), 256, 0, stream>>>(bufB, outp);
    }
}

// Round 8
// 630.602 us; speedup vs baseline: 1.7058x; 1.0592x over previous
//
#include <hip/hip_runtime.h>
#include <hip/hip_bf16.h>
#include <math.h>

#define NS   4      // batch
#define CH   128    // channels
#define HW   96     // full-res H=W
#define GS   48     // half-res grid side
#define LL   2304   // GS*GS
#define CKN  2048   // CH*16 (4x4 taps)
#define SCALE 10.0f
#define EPSSUM 0.1152f  // 1152 * 1e-4
#define PCH2 32     // softmax p-chunk
#define NCH2 72     // 2304/32

// per-sample strides (elements)
#define S_IN  ((size_t)CH * HW * HW)   // b / f / out
#define S_MK  ((size_t)HW * HW)        // mask
#define S_BS  ((size_t)CH * LL)        // bs_c / fs_c
#define S_PM  ((size_t)NCH2 * LL)      // pmax / psum
#define S_BUF ((size_t)LL * LL)        // bufA / bufB (fp32)
#define S_W2  ((size_t)CKN * LL)       // W2T (bf16 elems)
#define S_AT  ((size_t)LL * LL)        // attnT (bf16 elems)

typedef __attribute__((ext_vector_type(8))) short short8;
typedef __attribute__((ext_vector_type(4))) float float4v;

#define GLDS16(gptr, lptr) \
    __builtin_amdgcn_global_load_lds((const __attribute__((address_space(1))) void*)(gptr), \
        (__attribute__((address_space(3))) void*)(lptr), 16, 0, 0)

// ---------------- staging ----------------

__global__ __launch_bounds__(256) void k_stage(const float* __restrict__ b, const float* __restrict__ f,
                                               float* __restrict__ bs_c, float* __restrict__ fs_c) {
    int s = blockIdx.z;
    b += s * S_IN; f += s * S_IN; bs_c += s * S_BS; fs_c += s * S_BS;
    int c  = blockIdx.y;
    int rs = blockIdx.x * 256 + threadIdx.x;     // gridDim.x = 9
    int r = rs / GS, ss = rs % GS;
    int src = c * HW * HW + (2 * r) * HW + 2 * ss;
    bs_c[c * LL + rs] = b[src];
    fs_c[c * LL + rs] = f[src];
}

// partial ssq over 32 channels per block-row; ssq zeroed first (atomic accumulate)
__global__ __launch_bounds__(256) void k_ssq(const float* __restrict__ bs_c, float* __restrict__ ssq) {
    int s = blockIdx.z;
    bs_c += s * S_BS; ssq += (size_t)s * LL;
    int rs = blockIdx.x * 256 + threadIdx.x;
    int c0 = blockIdx.y * 32;
    float acc = 0.f;
    for (int c = c0; c < c0 + 32; ++c) { float v = bs_c[c * LL + rs]; acc += v * v; }
    atomicAdd(&ssq[rs], acc);
}

__global__ __launch_bounds__(256) void k_norm_mm(const float* __restrict__ ssq, const float* __restrict__ mk,
                                                 float* __restrict__ invn, float* __restrict__ mmv) {
    int sI = blockIdx.z;
    ssq += (size_t)sI * LL; mk += sI * S_MK; invn += (size_t)sI * LL; mmv += (size_t)sI * LL;
    int p = blockIdx.x * 256 + threadIdx.x;
    int ph = p / GS, pw = p % GS;
    float acc = EPSSUM;
    float msum = 0.f;
    for (int di = -1; di <= 1; ++di)
        for (int dj = -1; dj <= 1; ++dj) {
            int r = ph + di, s = pw + dj;
            if (r >= 0 && r < GS && s >= 0 && s < GS) {
                acc  += ssq[r * GS + s];
                msum += mk[(2 * r) * HW + 2 * s];
            }
        }
    invn[p] = 1.0f / sqrtf(acc);
    mmv[p]  = (msum / 9.0f == 1.0f) ? 1.0f : 0.0f;
}

// W2T[ck][p] = bf16( b[c, 2ph+dy-1, 2pw+dx-1] ), ck = c*16+dy*4+dx
__global__ __launch_bounds__(256) void k_w2T(const float* __restrict__ b, __hip_bfloat16* __restrict__ W2T) {
    int sI = blockIdx.z;
    b += sI * S_IN; W2T += sI * S_W2;
    int ck = blockIdx.y;
    int p  = blockIdx.x * 256 + threadIdx.x;     // gridDim.x = 9
    int c = ck >> 4, dy = (ck >> 2) & 3, dx = ck & 3;
    int ph = p / GS, pw = p % GS;
    int r = 2 * ph + dy - 1, s = 2 * pw + dx - 1;
    float v = 0.f;
    if (r >= 0 && r < HW && s >= 0 && s < HW) v = b[c * HW * HW + r * HW + s];
    W2T[(size_t)ck * LL + p] = __float2bfloat16(v);
}

// split fp32 [c][rs] -> transposed hi/lo bf16 [rs][c], into bufB scratch
__global__ __launch_bounds__(256) void k_split_T(const float* __restrict__ bs_c, const float* __restrict__ fs_c,
                                                 float* __restrict__ bufB) {
    __shared__ float tile[32][33];
    int z = blockIdx.z;
    int s = z >> 1, sel = z & 1;
    const float* X = (sel ? fs_c : bs_c) + s * S_BS;
    __hip_bfloat16* base = (__hip_bfloat16*)(bufB + s * S_BUF);
    __hip_bfloat16* hi = base + (size_t)sel * 2 * LL * CH;
    __hip_bfloat16* lo = hi + (size_t)LL * CH;
    int r0 = blockIdx.x * 32, c0 = blockIdx.y * 32;
    int tx = threadIdx.x & 31, ty = threadIdx.x >> 5;
#pragma unroll
    for (int j = 0; j < 4; ++j)
        tile[ty + 8 * j][tx] = X[(size_t)(c0 + ty + 8 * j) * LL + r0 + tx];
    __syncthreads();
#pragma unroll
    for (int j = 0; j < 4; ++j) {
        int rl = ty + 8 * j, cl = tx;
        float v = tile[cl][rl];
        __hip_bfloat16 h = __float2bfloat16(v);
        float resid = v - __bfloat162float(h);
        hi[(size_t)(r0 + rl) * CH + c0 + cl] = h;
        lo[(size_t)(r0 + rl) * CH + c0 + cl] = __float2bfloat16(resid);
    }
}

// ---------------- GEMM1 (split-bf16 MFMA): D = bs fs^T over channels ----------------
__global__ __launch_bounds__(256) void gemm1_mfma(const float* __restrict__ bufB, float* __restrict__ bufA) {
    __shared__ __hip_bfloat16 sAh[128 * 32];
    __shared__ __hip_bfloat16 sAl[128 * 32];
    __shared__ __hip_bfloat16 sBh[128 * 32];
    __shared__ __hip_bfloat16 sBl[128 * 32];
    int sI = blockIdx.z;
    const __hip_bfloat16* base = (const __hip_bfloat16*)(bufB + sI * S_BUF);
    const __hip_bfloat16* Ahi = base;
    const __hip_bfloat16* Alo = Ahi + (size_t)LL * CH;
    const __hip_bfloat16* Bhi = Alo + (size_t)LL * CH;
    const __hip_bfloat16* Blo = Bhi + (size_t)LL * CH;
    float* C = bufA + sI * S_BUF;

    int t = threadIdx.x, lane = t & 63, w = t >> 6;
    int wr = w >> 1, wc = w & 1;
    int m0 = blockIdx.y * 128, n0 = blockIdx.x * 128;

    float4v acc[4][4];
#pragma unroll
    for (int i = 0; i < 4; ++i)
#pragma unroll
        for (int j = 0; j < 4; ++j) acc[i][j] = (float4v){0.f, 0.f, 0.f, 0.f};

    for (int k0 = 0; k0 < 128; k0 += 32) {
#pragma unroll
        for (int it = 0; it < 2; ++it) {
            int chunk = it * 256 + w * 64 + lane;
            int row = chunk >> 2, ps = chunk & 3;
            int pd = ps ^ (row & 3);
            size_t ga = (size_t)(m0 + row) * 128 + k0 + pd * 8;
            size_t gb = (size_t)(n0 + row) * 128 + k0 + pd * 8;
            GLDS16(Ahi + ga, (char*)sAh + (size_t)chunk * 16);
            GLDS16(Alo + ga, (char*)sAl + (size_t)chunk * 16);
            GLDS16(Bhi + gb, (char*)sBh + (size_t)chunk * 16);
            GLDS16(Blo + gb, (char*)sBl + (size_t)chunk * 16);
        }
        __syncthreads();

        int lrow = lane & 15, part = lane >> 4;
        int sw = part ^ (lrow & 3);
        short8 ah[4], al[4], bh[4], bl[4];
#pragma unroll
        for (int i = 0; i < 4; ++i) {
            int slot = (wr * 64 + i * 16 + lrow) * 4 + sw;
            ah[i] = *reinterpret_cast<const short8*>(sAh + (size_t)slot * 8);
            al[i] = *reinterpret_cast<const short8*>(sAl + (size_t)slot * 8);
        }
#pragma unroll
        for (int j = 0; j < 4; ++j) {
            int slot = (wc * 64 + j * 16 + lrow) * 4 + sw;
            bh[j] = *reinterpret_cast<const short8*>(sBh + (size_t)slot * 8);
            bl[j] = *reinterpret_cast<const short8*>(sBl + (size_t)slot * 8);
        }
#pragma unroll
        for (int i = 0; i < 4; ++i)
#pragma unroll
            for (int j = 0; j < 4; ++j) {
                acc[i][j] = __builtin_amdgcn_mfma_f32_16x16x32_bf16(ah[i], bh[j], acc[i][j], 0, 0, 0);
                acc[i][j] = __builtin_amdgcn_mfma_f32_16x16x32_bf16(ah[i], bl[j], acc[i][j], 0, 0, 0);
                acc[i][j] = __builtin_amdgcn_mfma_f32_16x16x32_bf16(al[i], bh[j], acc[i][j], 0, 0, 0);
            }
        __syncthreads();
    }

    int col = lane & 15, rbase = (lane >> 4) * 4;
#pragma unroll
    for (int i = 0; i < 4; ++i)
#pragma unroll
        for (int j = 0; j < 4; ++j)
#pragma unroll
            for (int r = 0; r < 4; ++r) {
                int m = m0 + wr * 64 + i * 16 + rbase + r;
                int n = n0 + wc * 64 + j * 16 + col;
                C[(size_t)m * LL + n] = acc[i][j][r];
            }
}

// ---------------- GEMM2 (bf16 MFMA, bf16 output) ----------------
// Zb[q][ck] = bf16( sum_p attnT[q][p] * W2T[ck][p] ), K = LL = 2304.
__global__ __launch_bounds__(256) void gemm2_mfma(const __hip_bfloat16* __restrict__ attnT,
                                                  const __hip_bfloat16* __restrict__ W2T,
                                                  float* __restrict__ bufA) {
    __shared__ __hip_bfloat16 As[128 * 32];
    __shared__ __hip_bfloat16 Bs[128 * 32];
    int sI = blockIdx.z;
    const __hip_bfloat16* A = attnT + sI * S_AT;       // [LL][LL]
    const __hip_bfloat16* B = W2T + sI * S_W2;         // [CKN][LL]
    __hip_bfloat16* C = (__hip_bfloat16*)(bufA + sI * S_BUF);   // Zb [LL][CKN]

    int t = threadIdx.x;
    int lane = t & 63, w = t >> 6;
    int wr = w >> 1, wc = w & 1;
    int m0 = blockIdx.y * 128, n0 = blockIdx.x * 128;

    float4v acc[4][4];
#pragma unroll
    for (int i = 0; i < 4; ++i)
#pragma unroll
        for (int j = 0; j < 4; ++j) acc[i][j] = (float4v){0.f, 0.f, 0.f, 0.f};

    for (int k0 = 0; k0 < LL; k0 += 32) {
#pragma unroll
        for (int it = 0; it < 2; ++it) {
            int chunk = it * 256 + w * 64 + lane;
            int row = chunk >> 2, ps = chunk & 3;
            int pd = ps ^ (row & 3);
            const __hip_bfloat16* ga = A + (size_t)(m0 + row) * LL + k0 + pd * 8;
            const __hip_bfloat16* gb = B + (size_t)(n0 + row) * LL + k0 + pd * 8;
            GLDS16(ga, (char*)As + (size_t)chunk * 16);
            GLDS16(gb, (char*)Bs + (size_t)chunk * 16);
        }
        __syncthreads();

        int lrow = lane & 15, part = lane >> 4;
        int sw = part ^ (lrow & 3);
        short8 afrag[4], bfrag[4];
#pragma unroll
        for (int i = 0; i < 4; ++i) {
            int slot = (wr * 64 + i * 16 + lrow) * 4 + sw;
            afrag[i] = *reinterpret_cast<const short8*>(As + (size_t)slot * 8);
        }
#pragma unroll
        for (int j = 0; j < 4; ++j) {
            int slot = (wc * 64 + j * 16 + lrow) * 4 + sw;
            bfrag[j] = *reinterpret_cast<const short8*>(Bs + (size_t)slot * 8);
        }
#pragma unroll
        for (int i = 0; i < 4; ++i)
#pragma unroll
            for (int j = 0; j < 4; ++j)
                acc[i][j] = __builtin_amdgcn_mfma_f32_16x16x32_bf16(afrag[i], bfrag[j], acc[i][j], 0, 0, 0);
        __syncthreads();
    }

    int col = lane & 15, rbase = (lane >> 4) * 4;
#pragma unroll
    for (int i = 0; i < 4; ++i)
#pragma unroll
        for (int j = 0; j < 4; ++j)
#pragma unroll
            for (int r = 0; r < 4; ++r) {
                int m = m0 + wr * 64 + i * 16 + rbase + r;
                int n = n0 + wc * 64 + j * 16 + col;
                C[(size_t)m * CKN + n] = __float2bfloat16(acc[i][j][r]);
            }
}

// ---------------- correlation assembly + fuses (separate: fused 9-tap version was 2x slower) ----------------

__global__ __launch_bounds__(256) void k_corr(const float* __restrict__ bufA, const float* __restrict__ invn,
                                              float* __restrict__ bufB) {
    int sI = blockIdx.z;
    const float* D = bufA + sI * S_BUF;
    float* yi = bufB + sI * S_BUF;
    invn += (size_t)sI * LL;
    int p = blockIdx.y;
    int q = blockIdx.x * 256 + threadIdx.x;
    int ph = p / GS, pw = p % GS, qh = q / GS, qw = q % GS;
    float s = 0.f;
#pragma unroll
    for (int di = -1; di <= 1; ++di) {
        int rp = ph + di, tq = qh + di;
        if (rp < 0 || rp >= GS || tq < 0 || tq >= GS) continue;
#pragma unroll
        for (int dj = -1; dj <= 1; ++dj) {
            int sp = pw + dj, uq = qw + dj;
            if (sp < 0 || sp >= GS || uq < 0 || uq >= GS) continue;
            s += D[(size_t)(rp * GS + sp) * LL + (tq * GS + uq)];
        }
    }
    yi[(size_t)p * LL + q] = invn[p] * s;
}

__global__ __launch_bounds__(256) void k_fuse1(const float* __restrict__ bufB, float* __restrict__ bufA) {
    int sI = blockIdx.z;
    const float* yi = bufB + sI * S_BUF;
    float* S1 = bufA + sI * S_BUF;
    int a = blockIdx.y;
    int bcol = blockIdx.x * 256 + threadIdx.x;
    float s = 0.f;
#pragma unroll
    for (int d = -1; d <= 1; ++d) {
        int aa = a + d, bb = bcol + d;
        if (aa >= 0 && aa < LL && bb >= 0 && bb < LL) s += yi[(size_t)aa * LL + bb];
    }
    S1[(size_t)a * LL + bcol] = s;
}

__device__ __forceinline__ int gmap(int x) { int hi = x / GS; int lo = x - hi * GS; return lo * GS + hi; }

// fuse2 + softmax partials
__global__ __launch_bounds__(256) void k_fuse2_sm(const float* __restrict__ bufA, const float* __restrict__ mmv,
                                                  float* __restrict__ bufB,
                                                  float* __restrict__ pmax, float* __restrict__ psum) {
    int sI = blockIdx.z;
    const float* S1 = bufA + sI * S_BUF;
    float* S2 = bufB + sI * S_BUF;
    mmv += (size_t)sI * LL; pmax += sI * S_PM; psum += sI * S_PM;
    int q = blockIdx.x * 256 + threadIdx.x;
    int qh = q / GS, qw = q % GS;
    int b0 = qw * GS + qh;
    int p0 = blockIdx.y * PCH2;
    float mx = -1e30f, sm = 0.f;
    for (int i = 0; i < PCH2; ++i) {
        int p = p0 + i;
        int ph = p / GS, pw = p % GS;
        int a0 = pw * GS + ph;
        float s = 0.f;
#pragma unroll
        for (int e = -1; e <= 1; ++e) {
            int ae = a0 + e, be = b0 + e;
            if (ae >= 0 && ae < LL && be >= 0 && be < LL)
                s += S1[(size_t)gmap(ae) * LL + gmap(be)];
        }
        S2[(size_t)p * LL + q] = s;
        float lg = (mmv[p] != 0.f) ? SCALE * s : 0.f;
        float nm = fmaxf(mx, lg);
        sm = sm * __expf(mx - nm) + __expf(lg - nm);
        mx = nm;
    }
    pmax[blockIdx.y * LL + q] = mx;
    psum[blockIdx.y * LL + q] = sm;
}

// final softmax max/denominator: 4-way tree over 72 chunks, 64 q per block
__global__ __launch_bounds__(256) void k_sm2(const float* __restrict__ pmax, const float* __restrict__ psum,
                                             float* __restrict__ Mq, float* __restrict__ Dq) {
    __shared__ float red[4][64];
    int sI = blockIdx.z;
    pmax += sI * S_PM; psum += sI * S_PM; Mq += (size_t)sI * LL; Dq += (size_t)sI * LL;
    int t = threadIdx.x;
    int ql = t & 63, g = t >> 6;
    int q = blockIdx.x * 64 + ql;
    float mx = -1e30f;
    for (int ch = g * 18; ch < g * 18 + 18; ++ch) mx = fmaxf(mx, pmax[(size_t)ch * LL + q]);
    red[g][ql] = mx;
    __syncthreads();
    float mall = fmaxf(fmaxf(red[0][ql], red[1][ql]), fmaxf(red[2][ql], red[3][ql]));
    float sm = 0.f;
    for (int ch = g * 18; ch < g * 18 + 18; ++ch)
        sm += psum[(size_t)ch * LL + q] * __expf(pmax[(size_t)ch * LL + q] - mall);
    __syncthreads();
    red[g][ql] = sm;
    __syncthreads();
    if (g == 0) {
        Mq[q] = mall;
        Dq[q] = (red[0][ql] + red[1][ql]) + (red[2][ql] + red[3][ql]);
    }
}

// attnT[q][p] = bf16( mmv[p] * exp(10*S2[p][q] - Mq[q]) / Dq[q] ) via 32x32 LDS transpose
__global__ __launch_bounds__(256) void k_sm3T(const float* __restrict__ bufB, const float* __restrict__ mmv,
                                              const float* __restrict__ Mq, const float* __restrict__ Dq,
                                              __hip_bfloat16* __restrict__ attnT) {
    __shared__ float tile[32][33];
    int sI = blockIdx.z;
    const float* S2 = bufB + sI * S_BUF;
    mmv += (size_t)sI * LL; Mq += (size_t)sI * LL; Dq += (size_t)sI * LL; attnT += sI * S_AT;
    int tx = threadIdx.x & 31, ty = threadIdx.x >> 5;
    int p0 = blockIdx.y * 32, q0 = blockIdx.x * 32;
    int q = q0 + tx;
    float mq = Mq[q], dq = Dq[q];
#pragma unroll
    for (int j = 0; j < 4; ++j) {
        int p = p0 + ty + 8 * j;
        float v = S2[(size_t)p * LL + q];
        float attn = (mmv[p] != 0.f) ? __expf(SCALE * v - mq) / dq : 0.f;
        tile[ty + 8 * j][tx] = attn;
    }
    __syncthreads();
#pragma unroll
    for (int j = 0; j < 4; ++j) {
        int qq = q0 + ty + 8 * j;
        attnT[(size_t)qq * LL + p0 + tx] = __float2bfloat16(tile[tx][ty + 8 * j]);
    }
}

// ---------------- output assembly (reads bf16 Z) ----------------
__global__ __launch_bounds__(256) void k_out(const float* __restrict__ bufA, float* __restrict__ out) {
    int sI = blockIdx.z;
    const __hip_bfloat16* Z = (const __hip_bfloat16*)(bufA + sI * S_BUF);
    out += sI * S_IN;
    int c  = blockIdx.y;
    int yx = blockIdx.x * 256 + threadIdx.x;     // gridDim.x = 36
    int y = yx / HW, x = yx % HW;
    int u = y >> 1, a = y & 1, v = x >> 1, w = x & 1;
    int qh1 = u + a - 1, qh2 = u + a, qw1 = v + w - 1, qw2 = v + w;
    int cb = c * 16;
    float s = 0.f;
    if (qh1 >= 0) {
        if (qw1 >= 0)  s += __bfloat162float(Z[(size_t)(qh1 * GS + qw1) * CKN + cb + (3 - a) * 4 + (3 - w)]);
        if (qw2 < GS)  s += __bfloat162float(Z[(size_t)(qh1 * GS + qw2) * CKN + cb + (3 - a) * 4 + (1 - w)]);
    }
    if (qh2 < GS) {
        if (qw1 >= 0)  s += __bfloat162float(Z[(size_t)(qh2 * GS + qw1) * CKN + cb + (1 - a) * 4 + (3 - w)]);
        if (qw2 < GS)  s += __bfloat162float(Z[(size_t)(qh2 * GS + qw2) * CKN + cb + (1 - a) * 4 + (1 - w)]);
    }
    out[(size_t)c * HW * HW + yx] = 0.25f * s;
}

// ---------------- launch ----------------

extern "C" void kernel_launch(void* const* d_in, const int* in_sizes, int n_in,
                              void* d_out, int out_size, void* d_ws, size_t ws_size,
                              hipStream_t stream) {
    const float* b_all = (const float*)d_in[0];
    const float* f_all = (const float*)d_in[1];
    const float* m_all = (const float*)d_in[2];
    float* out = (float*)d_out;
    float* ws  = (float*)d_ws;

    const size_t perF = 2 * S_BS + 5 * (size_t)LL + 2 * S_PM + 2 * S_BUF + S_W2 / 2 + S_AT / 2;
    const size_t perB = perF * sizeof(float);
    int nb = (ws_size >= NS * perB) ? NS : ((ws_size >= 2 * perB) ? 2 : 1);

    size_t off = 0;
    float* bs_c = ws + off; off += nb * S_BS;
    float* fs_c = ws + off; off += nb * S_BS;
    float* ssq  = ws + off; off += nb * (size_t)LL;
    float* invn = ws + off; off += nb * (size_t)LL;
    float* mmv  = ws + off; off += nb * (size_t)LL;
    float* Mq   = ws + off; off += nb * (size_t)LL;
    float* Dq   = ws + off; off += nb * (size_t)LL;
    float* pmax = ws + off; off += nb * S_PM;
    float* psum = ws + off; off += nb * S_PM;
    float* bufA = ws + off; off += nb * S_BUF;   // D -> S1 -> Zb(bf16)
    float* bufB = ws + off; off += nb * S_BUF;   // (splits) -> yi -> S2
    __hip_bfloat16* W2T   = (__hip_bfloat16*)(ws + off); off += nb * S_W2 / 2;
    __hip_bfloat16* attnT = (__hip_bfloat16*)(ws + off); off += nb * S_AT / 2;

    for (int s0 = 0; s0 < NS; s0 += nb) {
        const float* b  = b_all + s0 * S_IN;
        const float* f  = f_all + s0 * S_IN;
        const float* mk = m_all + s0 * S_MK;
        float* outp = out + s0 * S_IN;

        hipMemsetAsync(ssq, 0, nb * LL * sizeof(float), stream);
        k_stage    <<<dim3(9, CH, nb), 256, 0, stream>>>(b, f, bs_c, fs_c);
        k_ssq      <<<dim3(9, 4, nb), 256, 0, stream>>>(bs_c, ssq);
        k_norm_mm  <<<dim3(9, 1, nb), 256, 0, stream>>>(ssq, mk, invn, mmv);
        k_w2T      <<<dim3(9, CKN, nb), 256, 0, stream>>>(b, W2T);
        k_split_T  <<<dim3(72, 4, 2 * nb), 256, 0, stream>>>(bs_c, fs_c, bufB);

        gemm1_mfma <<<dim3(18, 18, nb), 256, 0, stream>>>(bufB, bufA);
        k_corr     <<<dim3(9, LL, nb), 256, 0, stream>>>(bufA, invn, bufB);
        k_fuse1    <<<dim3(9, LL, nb), 256, 0, stream>>>(bufB, bufA);
        k_fuse2_sm <<<dim3(9, NCH2, nb), 256, 0, stream>>>(bufA, mmv, bufB, pmax, psum);

        k_sm2      <<<dim3(36, 1, nb), 256, 0, stream>>>(pmax, psum, Mq, Dq);
        k_sm3T     <<<dim3(72, 72, nb), 256, 0, stream>>>(bufB, mmv, Mq, Dq, attnT);

        gemm2_mfma <<<dim3(CKN / 128, LL / 128, nb), 256, 0, stream>>>(attnT, W2T, bufA);
        k_out      <<<dim3(36, CH, nb), 256, 0, stream>>>(bufA, outp);
    }
}

// Round 9
// 551.202 us; speedup vs baseline: 1.9515x; 1.1440x over previous
//
#include <hip/hip_runtime.h>
#include <hip/hip_bf16.h>
#include <math.h>

#define NS   4      // batch
#define CH   128    // channels
#define HW   96     // full-res H=W
#define GS   48     // half-res grid side
#define LL   2304   // GS*GS
#define CKN  2048   // CH*16 (4x4 taps)
#define SCALE 10.0f
#define EPSSUM 0.1152f  // 1152 * 1e-4
#define PCH2 32     // softmax p-chunk
#define NCH2 72     // 2304/32

// per-sample strides (elements)
#define S_IN  ((size_t)CH * HW * HW)   // b / f / out
#define S_MK  ((size_t)HW * HW)        // mask
#define S_BS  ((size_t)CH * LL)        // bs_c / fs_c
#define S_PM  ((size_t)NCH2 * LL)      // pmax / psum
#define S_BUF ((size_t)LL * LL)        // bufA / bufB (fp32)
#define S_W2  ((size_t)CKN * LL)       // W2T (bf16 elems)
#define S_AT  ((size_t)LL * LL)        // attnT (bf16 elems)

typedef __attribute__((ext_vector_type(8))) short short8;
typedef __attribute__((ext_vector_type(4))) float float4v;

#define GLDS16(gptr, lptr) \
    __builtin_amdgcn_global_load_lds((const __attribute__((address_space(1))) void*)(gptr), \
        (__attribute__((address_space(3))) void*)(lptr), 16, 0, 0)

__device__ __forceinline__ float4 ld4(const float* p) { return *reinterpret_cast<const float4*>(p); }

// ---------------- staging ----------------

__global__ __launch_bounds__(256) void k_stage(const float* __restrict__ b, const float* __restrict__ f,
                                               float* __restrict__ bs_c, float* __restrict__ fs_c) {
    int s = blockIdx.z;
    b += s * S_IN; f += s * S_IN; bs_c += s * S_BS; fs_c += s * S_BS;
    int c  = blockIdx.y;
    int rs = blockIdx.x * 256 + threadIdx.x;     // gridDim.x = 9
    int r = rs / GS, ss = rs % GS;
    int src = c * HW * HW + (2 * r) * HW + 2 * ss;
    bs_c[c * LL + rs] = b[src];
    fs_c[c * LL + rs] = f[src];
}

// partial ssq over 32 channels per block-row; ssq zeroed first (atomic accumulate)
__global__ __launch_bounds__(256) void k_ssq(const float* __restrict__ bs_c, float* __restrict__ ssq) {
    int s = blockIdx.z;
    bs_c += s * S_BS; ssq += (size_t)s * LL;
    int rs = blockIdx.x * 256 + threadIdx.x;
    int c0 = blockIdx.y * 32;
    float acc = 0.f;
    for (int c = c0; c < c0 + 32; ++c) { float v = bs_c[c * LL + rs]; acc += v * v; }
    atomicAdd(&ssq[rs], acc);
}

__global__ __launch_bounds__(256) void k_norm_mm(const float* __restrict__ ssq, const float* __restrict__ mk,
                                                 float* __restrict__ invn, float* __restrict__ mmv) {
    int sI = blockIdx.z;
    ssq += (size_t)sI * LL; mk += sI * S_MK; invn += (size_t)sI * LL; mmv += (size_t)sI * LL;
    int p = blockIdx.x * 256 + threadIdx.x;
    int ph = p / GS, pw = p % GS;
    float acc = EPSSUM;
    float msum = 0.f;
    for (int di = -1; di <= 1; ++di)
        for (int dj = -1; dj <= 1; ++dj) {
            int r = ph + di, s = pw + dj;
            if (r >= 0 && r < GS && s >= 0 && s < GS) {
                acc  += ssq[r * GS + s];
                msum += mk[(2 * r) * HW + 2 * s];
            }
        }
    invn[p] = 1.0f / sqrtf(acc);
    mmv[p]  = (msum / 9.0f == 1.0f) ? 1.0f : 0.0f;
}

// W2T[ck][p] = bf16( b[c, 2ph+dy-1, 2pw+dx-1] ), ck = c*16+dy*4+dx
__global__ __launch_bounds__(256) void k_w2T(const float* __restrict__ b, __hip_bfloat16* __restrict__ W2T) {
    int sI = blockIdx.z;
    b += sI * S_IN; W2T += sI * S_W2;
    int ck = blockIdx.y;
    int p  = blockIdx.x * 256 + threadIdx.x;     // gridDim.x = 9
    int c = ck >> 4, dy = (ck >> 2) & 3, dx = ck & 3;
    int ph = p / GS, pw = p % GS;
    int r = 2 * ph + dy - 1, s = 2 * pw + dx - 1;
    float v = 0.f;
    if (r >= 0 && r < HW && s >= 0 && s < HW) v = b[c * HW * HW + r * HW + s];
    W2T[(size_t)ck * LL + p] = __float2bfloat16(v);
}

// split fp32 [c][rs] -> transposed hi/lo bf16 [rs][c], into bufB scratch
__global__ __launch_bounds__(256) void k_split_T(const float* __restrict__ bs_c, const float* __restrict__ fs_c,
                                                 float* __restrict__ bufB) {
    __shared__ float tile[32][33];
    int z = blockIdx.z;
    int s = z >> 1, sel = z & 1;
    const float* X = (sel ? fs_c : bs_c) + s * S_BS;
    __hip_bfloat16* base = (__hip_bfloat16*)(bufB + s * S_BUF);
    __hip_bfloat16* hi = base + (size_t)sel * 2 * LL * CH;
    __hip_bfloat16* lo = hi + (size_t)LL * CH;
    int r0 = blockIdx.x * 32, c0 = blockIdx.y * 32;
    int tx = threadIdx.x & 31, ty = threadIdx.x >> 5;
#pragma unroll
    for (int j = 0; j < 4; ++j)
        tile[ty + 8 * j][tx] = X[(size_t)(c0 + ty + 8 * j) * LL + r0 + tx];
    __syncthreads();
#pragma unroll
    for (int j = 0; j < 4; ++j) {
        int rl = ty + 8 * j, cl = tx;
        float v = tile[cl][rl];
        __hip_bfloat16 h = __float2bfloat16(v);
        float resid = v - __bfloat162float(h);
        hi[(size_t)(r0 + rl) * CH + c0 + cl] = h;
        lo[(size_t)(r0 + rl) * CH + c0 + cl] = __float2bfloat16(resid);
    }
}

// ---------------- GEMM1 (split-bf16 MFMA): D = bs fs^T over channels ----------------
__global__ __launch_bounds__(256) void gemm1_mfma(const float* __restrict__ bufB, float* __restrict__ bufA) {
    __shared__ __hip_bfloat16 sAh[128 * 32];
    __shared__ __hip_bfloat16 sAl[128 * 32];
    __shared__ __hip_bfloat16 sBh[128 * 32];
    __shared__ __hip_bfloat16 sBl[128 * 32];
    int sI = blockIdx.z;
    const __hip_bfloat16* base = (const __hip_bfloat16*)(bufB + sI * S_BUF);
    const __hip_bfloat16* Ahi = base;
    const __hip_bfloat16* Alo = Ahi + (size_t)LL * CH;
    const __hip_bfloat16* Bhi = Alo + (size_t)LL * CH;
    const __hip_bfloat16* Blo = Bhi + (size_t)LL * CH;
    float* C = bufA + sI * S_BUF;

    int t = threadIdx.x, lane = t & 63, w = t >> 6;
    int wr = w >> 1, wc = w & 1;
    int m0 = blockIdx.y * 128, n0 = blockIdx.x * 128;

    float4v acc[4][4];
#pragma unroll
    for (int i = 0; i < 4; ++i)
#pragma unroll
        for (int j = 0; j < 4; ++j) acc[i][j] = (float4v){0.f, 0.f, 0.f, 0.f};

    for (int k0 = 0; k0 < 128; k0 += 32) {
#pragma unroll
        for (int it = 0; it < 2; ++it) {
            int chunk = it * 256 + w * 64 + lane;
            int row = chunk >> 2, ps = chunk & 3;
            int pd = ps ^ (row & 3);
            size_t ga = (size_t)(m0 + row) * 128 + k0 + pd * 8;
            size_t gb = (size_t)(n0 + row) * 128 + k0 + pd * 8;
            GLDS16(Ahi + ga, (char*)sAh + (size_t)chunk * 16);
            GLDS16(Alo + ga, (char*)sAl + (size_t)chunk * 16);
            GLDS16(Bhi + gb, (char*)sBh + (size_t)chunk * 16);
            GLDS16(Blo + gb, (char*)sBl + (size_t)chunk * 16);
        }
        __syncthreads();

        int lrow = lane & 15, part = lane >> 4;
        int sw = part ^ (lrow & 3);
        short8 ah[4], al[4], bh[4], bl[4];
#pragma unroll
        for (int i = 0; i < 4; ++i) {
            int slot = (wr * 64 + i * 16 + lrow) * 4 + sw;
            ah[i] = *reinterpret_cast<const short8*>(sAh + (size_t)slot * 8);
            al[i] = *reinterpret_cast<const short8*>(sAl + (size_t)slot * 8);
        }
#pragma unroll
        for (int j = 0; j < 4; ++j) {
            int slot = (wc * 64 + j * 16 + lrow) * 4 + sw;
            bh[j] = *reinterpret_cast<const short8*>(sBh + (size_t)slot * 8);
            bl[j] = *reinterpret_cast<const short8*>(sBl + (size_t)slot * 8);
        }
#pragma unroll
        for (int i = 0; i < 4; ++i)
#pragma unroll
            for (int j = 0; j < 4; ++j) {
                acc[i][j] = __builtin_amdgcn_mfma_f32_16x16x32_bf16(ah[i], bh[j], acc[i][j], 0, 0, 0);
                acc[i][j] = __builtin_amdgcn_mfma_f32_16x16x32_bf16(ah[i], bl[j], acc[i][j], 0, 0, 0);
                acc[i][j] = __builtin_amdgcn_mfma_f32_16x16x32_bf16(al[i], bh[j], acc[i][j], 0, 0, 0);
            }
        __syncthreads();
    }

    int col = lane & 15, rbase = (lane >> 4) * 4;
#pragma unroll
    for (int i = 0; i < 4; ++i)
#pragma unroll
        for (int j = 0; j < 4; ++j)
#pragma unroll
            for (int r = 0; r < 4; ++r) {
                int m = m0 + wr * 64 + i * 16 + rbase + r;
                int n = n0 + wc * 64 + j * 16 + col;
                C[(size_t)m * LL + n] = acc[i][j][r];
            }
}

// ---------------- GEMM2 (bf16 MFMA, bf16 output) ----------------
__global__ __launch_bounds__(256) void gemm2_mfma(const __hip_bfloat16* __restrict__ attnT,
                                                  const __hip_bfloat16* __restrict__ W2T,
                                                  float* __restrict__ bufA) {
    __shared__ __hip_bfloat16 As[128 * 32];
    __shared__ __hip_bfloat16 Bs[128 * 32];
    int sI = blockIdx.z;
    const __hip_bfloat16* A = attnT + sI * S_AT;       // [LL][LL]
    const __hip_bfloat16* B = W2T + sI * S_W2;         // [CKN][LL]
    __hip_bfloat16* C = (__hip_bfloat16*)(bufA + sI * S_BUF);   // Zb [LL][CKN]

    int t = threadIdx.x;
    int lane = t & 63, w = t >> 6;
    int wr = w >> 1, wc = w & 1;
    int m0 = blockIdx.y * 128, n0 = blockIdx.x * 128;

    float4v acc[4][4];
#pragma unroll
    for (int i = 0; i < 4; ++i)
#pragma unroll
        for (int j = 0; j < 4; ++j) acc[i][j] = (float4v){0.f, 0.f, 0.f, 0.f};

    for (int k0 = 0; k0 < LL; k0 += 32) {
#pragma unroll
        for (int it = 0; it < 2; ++it) {
            int chunk = it * 256 + w * 64 + lane;
            int row = chunk >> 2, ps = chunk & 3;
            int pd = ps ^ (row & 3);
            const __hip_bfloat16* ga = A + (size_t)(m0 + row) * LL + k0 + pd * 8;
            const __hip_bfloat16* gb = B + (size_t)(n0 + row) * LL + k0 + pd * 8;
            GLDS16(ga, (char*)As + (size_t)chunk * 16);
            GLDS16(gb, (char*)Bs + (size_t)chunk * 16);
        }
        __syncthreads();

        int lrow = lane & 15, part = lane >> 4;
        int sw = part ^ (lrow & 3);
        short8 afrag[4], bfrag[4];
#pragma unroll
        for (int i = 0; i < 4; ++i) {
            int slot = (wr * 64 + i * 16 + lrow) * 4 + sw;
            afrag[i] = *reinterpret_cast<const short8*>(As + (size_t)slot * 8);
        }
#pragma unroll
        for (int j = 0; j < 4; ++j) {
            int slot = (wc * 64 + j * 16 + lrow) * 4 + sw;
            bfrag[j] = *reinterpret_cast<const short8*>(Bs + (size_t)slot * 8);
        }
#pragma unroll
        for (int i = 0; i < 4; ++i)
#pragma unroll
            for (int j = 0; j < 4; ++j)
                acc[i][j] = __builtin_amdgcn_mfma_f32_16x16x32_bf16(afrag[i], bfrag[j], acc[i][j], 0, 0, 0);
        __syncthreads();
    }

    int col = lane & 15, rbase = (lane >> 4) * 4;
#pragma unroll
    for (int i = 0; i < 4; ++i)
#pragma unroll
        for (int j = 0; j < 4; ++j)
#pragma unroll
            for (int r = 0; r < 4; ++r) {
                int m = m0 + wr * 64 + i * 16 + rbase + r;
                int n = n0 + wc * 64 + j * 16 + col;
                C[(size_t)m * CKN + n] = __float2bfloat16(acc[i][j][r]);
            }
}

// ---------------- correlation assembly (float4-vectorized) ----------------
// yi[p][q] = invn[p] * sum_{valid di,dj} D[p+48di+dj][q+48di+dj]
// 4 q's per thread (q4 4-aligned; group shares qh since 48%4==0). Aligned b128
// loads; the +-1 column shift recombined in registers (L/C/R trick).
__global__ __launch_bounds__(192) void k_corr_v4(const float* __restrict__ bufA, const float* __restrict__ invn,
                                                 float* __restrict__ bufB) {
    int sI = blockIdx.z;
    const float* D = bufA + sI * S_BUF;
    float* yi = bufB + sI * S_BUF;
    invn += (size_t)sI * LL;

    int p  = blockIdx.y;
    int qi = blockIdx.x * 192 + threadIdx.x;     // 0..575
    int q4 = qi * 4;
    int qh = q4 / GS, qw0 = q4 % GS;
    int ph = p / GS, pw = p % GS;

    float4 acc = {0.f, 0.f, 0.f, 0.f};
#pragma unroll
    for (int di = -1; di <= 1; ++di) {
        int rp = ph + di, tq = qh + di;
        if (rp < 0 || rp >= GS || tq < 0 || tq >= GS) continue;
        int r0 = rp * GS + pw;           // = p + 48*di
        int c0 = tq * GS + qw0;          // = q4 + 48*di (4-aligned)
        // dj = 0
        {
            float4 Cc = ld4(D + (size_t)r0 * LL + c0);
            acc.x += Cc.x; acc.y += Cc.y; acc.z += Cc.z; acc.w += Cc.w;
        }
        // dj = -1 (row r0-1, cols c0-1..c0+2); valid iff pw>0; elem0 masked iff qw0==0
        if (pw > 0) {
            const float* rowm = D + (size_t)(r0 - 1) * LL;
            float4 L  = ld4(rowm + (qw0 > 0 ? c0 - 4 : c0));
            float4 Cm = ld4(rowm + c0);
            acc.x += (qw0 > 0 ? L.w : 0.f);
            acc.y += Cm.x; acc.z += Cm.y; acc.w += Cm.z;
        }
        // dj = +1 (row r0+1, cols c0+1..c0+4); valid iff pw<47; elem3 masked iff qw0==44
        if (pw < GS - 1) {
            const float* rowp = D + (size_t)(r0 + 1) * LL;
            float4 Cp = ld4(rowp + c0);
            float4 R  = ld4(rowp + (qw0 < GS - 4 ? c0 + 4 : c0));
            acc.x += Cp.y; acc.y += Cp.z; acc.z += Cp.w;
            acc.w += (qw0 < GS - 4 ? R.x : 0.f);
        }
    }
    float inv = invn[p];
    float4 outv = {inv * acc.x, inv * acc.y, inv * acc.z, inv * acc.w};
    *reinterpret_cast<float4*>(yi + (size_t)p * LL + q4) = outv;
}

// ---------------- fuse1 (float4-vectorized): S1[a][b] = sum_d yi[a+d][b+d] ----------------
__global__ __launch_bounds__(192) void k_fuse1_v4(const float* __restrict__ bufB, float* __restrict__ bufA) {
    int sI = blockIdx.z;
    const float* yi = bufB + sI * S_BUF;
    float* S1 = bufA + sI * S_BUF;
    int a  = blockIdx.y;
    int bi = blockIdx.x * 192 + threadIdx.x;
    int b4 = bi * 4;

    float4 acc = ld4(yi + (size_t)a * LL + b4);          // d = 0
    if (a > 0) {                                          // d = -1: cols b4-1..b4+2
        const float* rowm = yi + (size_t)(a - 1) * LL;
        float4 L  = ld4(rowm + (b4 > 0 ? b4 - 4 : b4));
        float4 Cm = ld4(rowm + b4);
        acc.x += (b4 > 0 ? L.w : 0.f);
        acc.y += Cm.x; acc.z += Cm.y; acc.w += Cm.z;
    }
    if (a < LL - 1) {                                     // d = +1: cols b4+1..b4+4
        const float* rowp = yi + (size_t)(a + 1) * LL;
        float4 Cp = ld4(rowp + b4);
        float4 R  = ld4(rowp + (b4 < LL - 4 ? b4 + 4 : b4));
        acc.x += Cp.y; acc.y += Cp.z; acc.z += Cp.w;
        acc.w += (b4 < LL - 4 ? R.x : 0.f);
    }
    *reinterpret_cast<float4*>(S1 + (size_t)a * LL + b4) = acc;
}

__device__ __forceinline__ int gmap(int x) { int hi = x / GS; int lo = x - hi * GS; return lo * GS + hi; }

// fuse2 + softmax partials
__global__ __launch_bounds__(256) void k_fuse2_sm(const float* __restrict__ bufA, const float* __restrict__ mmv,
                                                  float* __restrict__ bufB,
                                                  float* __restrict__ pmax, float* __restrict__ psum) {
    int sI = blockIdx.z;
    const float* S1 = bufA + sI * S_BUF;
    float* S2 = bufB + sI * S_BUF;
    mmv += (size_t)sI * LL; pmax += sI * S_PM; psum += sI * S_PM;
    int q = blockIdx.x * 256 + threadIdx.x;
    int qh = q / GS, qw = q % GS;
    int b0 = qw * GS + qh;
    int p0 = blockIdx.y * PCH2;
    float mx = -1e30f, sm = 0.f;
    for (int i = 0; i < PCH2; ++i) {
        int p = p0 + i;
        int ph = p / GS, pw = p % GS;
        int a0 = pw * GS + ph;
        float s = 0.f;
#pragma unroll
        for (int e = -1; e <= 1; ++e) {
            int ae = a0 + e, be = b0 + e;
            if (ae >= 0 && ae < LL && be >= 0 && be < LL)
                s += S1[(size_t)gmap(ae) * LL + gmap(be)];
        }
        S2[(size_t)p * LL + q] = s;
        float lg = (mmv[p] != 0.f) ? SCALE * s : 0.f;
        float nm = fmaxf(mx, lg);
        sm = sm * __expf(mx - nm) + __expf(lg - nm);
        mx = nm;
    }
    pmax[blockIdx.y * LL + q] = mx;
    psum[blockIdx.y * LL + q] = sm;
}

// final softmax max/denominator: 4-way tree over 72 chunks, 64 q per block
__global__ __launch_bounds__(256) void k_sm2(const float* __restrict__ pmax, const float* __restrict__ psum,
                                             float* __restrict__ Mq, float* __restrict__ Dq) {
    __shared__ float red[4][64];
    int sI = blockIdx.z;
    pmax += sI * S_PM; psum += sI * S_PM; Mq += (size_t)sI * LL; Dq += (size_t)sI * LL;
    int t = threadIdx.x;
    int ql = t & 63, g = t >> 6;
    int q = blockIdx.x * 64 + ql;
    float mx = -1e30f;
    for (int ch = g * 18; ch < g * 18 + 18; ++ch) mx = fmaxf(mx, pmax[(size_t)ch * LL + q]);
    red[g][ql] = mx;
    __syncthreads();
    float mall = fmaxf(fmaxf(red[0][ql], red[1][ql]), fmaxf(red[2][ql], red[3][ql]));
    float sm = 0.f;
    for (int ch = g * 18; ch < g * 18 + 18; ++ch)
        sm += psum[(size_t)ch * LL + q] * __expf(pmax[(size_t)ch * LL + q] - mall);
    __syncthreads();
    red[g][ql] = sm;
    __syncthreads();
    if (g == 0) {
        Mq[q] = mall;
        Dq[q] = (red[0][ql] + red[1][ql]) + (red[2][ql] + red[3][ql]);
    }
}

// attnT[q][p] = bf16( mmv[p] * exp(10*S2[p][q] - Mq[q]) / Dq[q] ) via 32x32 LDS transpose
__global__ __launch_bounds__(256) void k_sm3T(const float* __restrict__ bufB, const float* __restrict__ mmv,
                                              const float* __restrict__ Mq, const float* __restrict__ Dq,
                                              __hip_bfloat16* __restrict__ attnT) {
    __shared__ float tile[32][33];
    int sI = blockIdx.z;
    const float* S2 = bufB + sI * S_BUF;
    mmv += (size_t)sI * LL; Mq += (size_t)sI * LL; Dq += (size_t)sI * LL; attnT += sI * S_AT;
    int tx = threadIdx.x & 31, ty = threadIdx.x >> 5;
    int p0 = blockIdx.y * 32, q0 = blockIdx.x * 32;
    int q = q0 + tx;
    float mq = Mq[q], dq = Dq[q];
#pragma unroll
    for (int j = 0; j < 4; ++j) {
        int p = p0 + ty + 8 * j;
        float v = S2[(size_t)p * LL + q];
        float attn = (mmv[p] != 0.f) ? __expf(SCALE * v - mq) / dq : 0.f;
        tile[ty + 8 * j][tx] = attn;
    }
    __syncthreads();
#pragma unroll
    for (int j = 0; j < 4; ++j) {
        int qq = q0 + ty + 8 * j;
        attnT[(size_t)qq * LL + p0 + tx] = __float2bfloat16(tile[tx][ty + 8 * j]);
    }
}

// ---------------- output assembly (reads bf16 Z) ----------------
__global__ __launch_bounds__(256) void k_out(const float* __restrict__ bufA, float* __restrict__ out) {
    int sI = blockIdx.z;
    const __hip_bfloat16* Z = (const __hip_bfloat16*)(bufA + sI * S_BUF);
    out += sI * S_IN;
    int c  = blockIdx.y;
    int yx = blockIdx.x * 256 + threadIdx.x;     // gridDim.x = 36
    int y = yx / HW, x = yx % HW;
    int u = y >> 1, a = y & 1, v = x >> 1, w = x & 1;
    int qh1 = u + a - 1, qh2 = u + a, qw1 = v + w - 1, qw2 = v + w;
    int cb = c * 16;
    float s = 0.f;
    if (qh1 >= 0) {
        if (qw1 >= 0)  s += __bfloat162float(Z[(size_t)(qh1 * GS + qw1) * CKN + cb + (3 - a) * 4 + (3 - w)]);
        if (qw2 < GS)  s += __bfloat162float(Z[(size_t)(qh1 * GS + qw2) * CKN + cb + (3 - a) * 4 + (1 - w)]);
    }
    if (qh2 < GS) {
        if (qw1 >= 0)  s += __bfloat162float(Z[(size_t)(qh2 * GS + qw1) * CKN + cb + (1 - a) * 4 + (3 - w)]);
        if (qw2 < GS)  s += __bfloat162float(Z[(size_t)(qh2 * GS + qw2) * CKN + cb + (1 - a) * 4 + (1 - w)]);
    }
    out[(size_t)c * HW * HW + yx] = 0.25f * s;
}

// ---------------- launch ----------------

extern "C" void kernel_launch(void* const* d_in, const int* in_sizes, int n_in,
                              void* d_out, int out_size, void* d_ws, size_t ws_size,
                              hipStream_t stream) {
    const float* b_all = (const float*)d_in[0];
    const float* f_all = (const float*)d_in[1];
    const float* m_all = (const float*)d_in[2];
    float* out = (float*)d_out;
    float* ws  = (float*)d_ws;

    const size_t perF = 2 * S_BS + 5 * (size_t)LL + 2 * S_PM + 2 * S_BUF + S_W2 / 2 + S_AT / 2;
    const size_t perB = perF * sizeof(float);
    int nb = (ws_size >= NS * perB) ? NS : ((ws_size >= 2 * perB) ? 2 : 1);

    size_t off = 0;
    float* bs_c = ws + off; off += nb * S_BS;
    float* fs_c = ws + off; off += nb * S_BS;
    float* ssq  = ws + off; off += nb * (size_t)LL;
    float* invn = ws + off; off += nb * (size_t)LL;
    float* mmv  = ws + off; off += nb * (size_t)LL;
    float* Mq   = ws + off; off += nb * (size_t)LL;
    float* Dq   = ws + off; off += nb * (size_t)LL;
    float* pmax = ws + off; off += nb * S_PM;
    float* psum = ws + off; off += nb * S_PM;
    float* bufA = ws + off; off += nb * S_BUF;   // D -> S1 -> Zb(bf16)
    float* bufB = ws + off; off += nb * S_BUF;   // (splits) -> yi -> S2
    __hip_bfloat16* W2T   = (__hip_bfloat16*)(ws + off); off += nb * S_W2 / 2;
    __hip_bfloat16* attnT = (__hip_bfloat16*)(ws + off); off += nb * S_AT / 2;

    for (int s0 = 0; s0 < NS; s0 += nb) {
        const float* b  = b_all + s0 * S_IN;
        const float* f  = f_all + s0 * S_IN;
        const float* mk = m_all + s0 * S_MK;
        float* outp = out + s0 * S_IN;

        hipMemsetAsync(ssq, 0, nb * LL * sizeof(float), stream);
        k_stage    <<<dim3(9, CH, nb), 256, 0, stream>>>(b, f, bs_c, fs_c);
        k_ssq      <<<dim3(9, 4, nb), 256, 0, stream>>>(bs_c, ssq);
        k_norm_mm  <<<dim3(9, 1, nb), 256, 0, stream>>>(ssq, mk, invn, mmv);
        k_w2T      <<<dim3(9, CKN, nb), 256, 0, stream>>>(b, W2T);
        k_split_T  <<<dim3(72, 4, 2 * nb), 256, 0, stream>>>(bs_c, fs_c, bufB);

        gemm1_mfma <<<dim3(18, 18, nb), 256, 0, stream>>>(bufB, bufA);
        k_corr_v4  <<<dim3(3, LL, nb), 192, 0, stream>>>(bufA, invn, bufB);
        k_fuse1_v4 <<<dim3(3, LL, nb), 192, 0, stream>>>(bufB, bufA);
        k_fuse2_sm <<<dim3(9, NCH2, nb), 256, 0, stream>>>(bufA, mmv, bufB, pmax, psum);

        k_sm2      <<<dim3(36, 1, nb), 256, 0, stream>>>(pmax, psum, Mq, Dq);
        k_sm3T     <<<dim3(72, 72, nb), 256, 0, stream>>>(bufB, mmv, Mq, Dq, attnT);

        gemm2_mfma <<<dim3(CKN / 128, LL / 128, nb), 256, 0, stream>>>(attnT, W2T, bufA);
        k_out      <<<dim3(36, CH, nb), 256, 0, stream>>>(bufA, outp);
    }
}